// Round 12
// baseline (269.353 us; speedup 1.0000x reference)
//
#include <hip/hip_runtime.h>
#include <hip/hip_bf16.h>

#define DEVINL __device__ __forceinline__

typedef float f32x4 __attribute__((ext_vector_type(4)));
typedef __bf16 bf16x8 __attribute__((ext_vector_type(8)));

DEVINL void gld_lds16(const void* g, void* l) {
  __builtin_amdgcn_global_load_lds(
      (const __attribute__((address_space(1))) unsigned int*)g,
      (__attribute__((address_space(3))) unsigned int*)l, 16, 0, 0);
}

DEVINL unsigned short f2bf(float f) {
  __bf16 h = (__bf16)f;
  return __builtin_bit_cast(unsigned short, h);
}

DEVINL f32x4 mfma16(bf16x8 a, bf16x8 b, f32x4 c) {
  return __builtin_amdgcn_mfma_f32_16x16x32_bf16(a, b, c, 0, 0, 0);
}

// XCD-aware bijective block remap (nwg divisible by 8).
DEVINL void swz3(int& bn, int& bm, int& z) {
  int gx = gridDim.x, gy = gridDim.y;
  int nwg = gx * gy * gridDim.z;
  int flat = blockIdx.x + gx * (blockIdx.y + gy * blockIdx.z);
  int wg = (flat & 7) * (nwg >> 3) + (flat >> 3);
  bn = wg % gx;
  int t = wg / gx;
  bm = t % gy;
  z = t / gy;
}

// ---------------------------------------------------------------------------
// fp32 -> bf16 convert, both activations in one launch (grid 8192 x 256)
// ---------------------------------------------------------------------------
__global__ __launch_bounds__(256) void cvt2_kernel(const float* __restrict__ inA,
                                                   unsigned short* __restrict__ outA,
                                                   const float* __restrict__ inB,
                                                   unsigned short* __restrict__ outB) {
  int bx = blockIdx.x;
  const float* in = bx < 4096 ? inA : inB;
  unsigned short* outp = bx < 4096 ? outA : outB;
  int i = (bx & 4095) * 256 + threadIdx.x;
  float4 v = ((const float4*)in)[i];
  ushort4 o;
  o.x = f2bf(v.x); o.y = f2bf(v.y); o.z = f2bf(v.z); o.w = f2bf(v.w);
  ((ushort4*)outp)[i] = o;
}

// ---------------------------------------------------------------------------
// All 5 weight transposes (W[K][N] fp32 -> Wt[N][K] bf16) in one launch.
// ---------------------------------------------------------------------------
struct TransArgs {
  const float* W[5];
  unsigned short* Wt[5];
};

DEVINL void trans_tile(const float* W, unsigned short* Wt, int K, int N,
                       int xt, int yt) {
  __shared__ float t[32][33];
  int n0 = xt * 32, k0 = yt * 32;
  int tx = threadIdx.x & 31, ty = threadIdx.x >> 5;  // ty 0..7
#pragma unroll
  for (int i = 0; i < 4; i++)
    t[ty + i * 8][tx] = W[(size_t)(k0 + ty + i * 8) * N + n0 + tx];
  __syncthreads();
#pragma unroll
  for (int i = 0; i < 4; i++) {
    int n = ty + i * 8;
    Wt[(size_t)(n0 + n) * K + k0 + tx] = f2bf(t[tx][n]);
  }
}

__global__ __launch_bounds__(256) void transpose_all(TransArgs a) {
  int t = blockIdx.x;
  if (t < 1024)       trans_tile(a.W[0], a.Wt[0], 1024, 1024, t % 32, t / 32);
  else if (t < 3072)  { int l = t - 1024; trans_tile(a.W[1], a.Wt[1], 1024, 2048, l % 64, l / 64); }
  else if (t < 4096)  { int l = t - 3072; trans_tile(a.W[2], a.Wt[2], 1024, 1024, l % 32, l / 32); }
  else if (t < 6144)  { int l = t - 4096; trans_tile(a.W[3], a.Wt[3], 1024, 2048, l % 64, l / 64); }
  else                { int l = t - 6144; trans_tile(a.W[4], a.Wt[4], 2048, 1024, l % 32, l / 32); }
}

// ---------------------------------------------------------------------------
// 8-wave GEMM main loop (BM x BN tile, BK=64, 512 threads, waves 2M x 4N).
// T2 XOR swizzle; double-buffered, one barrier per K-step (m97 order).
// ---------------------------------------------------------------------------
template <int BM, int BN, int MREP, int NREP>
DEVINL void g256_main(const unsigned short* A, const unsigned short* Bt, int K,
                      int bm, int bn, unsigned short* Al, unsigned short* Bl,
                      f32x4 (&acc)[MREP][NREP]) {
  const int tid = threadIdx.x;
  const int wave = tid >> 6, lane = tid & 63;
  const int lr = lane & 15;
  const int lk16 = (lane >> 4) * 16;
  const int wm = wave >> 2, wn = wave & 3;
  const int swz = (lr & 7) << 4;
  const int nk = K >> 6;
  const size_t Kb = (size_t)K * 2;

#pragma unroll
  for (int m = 0; m < MREP; m++)
#pragma unroll
    for (int n = 0; n < NREP; n++) acc[m][n] = f32x4{0.f, 0.f, 0.f, 0.f};

  auto stage = [&](int buf, int kt) {
#pragma unroll
    for (int i = 0; i < BM / 64; i++) {
      int chunk = i * 512 + tid;
      int row = chunk >> 3, cb = (chunk & 7) * 16;
      const char* src = (const char*)A + (size_t)(bm * BM + row) * Kb +
                        kt * 128 + (cb ^ ((row & 7) << 4));
      char* dst = (char*)(Al + (size_t)buf * BM * 64) + (i * 512 + wave * 64) * 16;
      gld_lds16(src, dst);
    }
#pragma unroll
    for (int i = 0; i < BN / 64; i++) {
      int chunk = i * 512 + tid;
      int row = chunk >> 3, cb = (chunk & 7) * 16;
      const char* src = (const char*)Bt + (size_t)(bn * BN + row) * Kb +
                        kt * 128 + (cb ^ ((row & 7) << 4));
      char* dst = (char*)(Bl + (size_t)buf * BN * 64) + (i * 512 + wave * 64) * 16;
      gld_lds16(src, dst);
    }
  };

  stage(0, 0);
  for (int kt = 0; kt < nk; ++kt) {
    __syncthreads();
    if (kt + 1 < nk) stage((kt + 1) & 1, kt + 1);
    const char* ab = (const char*)(Al + (size_t)(kt & 1) * BM * 64);
    const char* bb = (const char*)(Bl + (size_t)(kt & 1) * BN * 64);
#pragma unroll
    for (int kk = 0; kk < 2; kk++) {
      bf16x8 af[MREP], bf[NREP];
#pragma unroll
      for (int m = 0; m < MREP; m++) {
        int row = wm * (BM / 2) + m * 16 + lr;
        af[m] = *(const bf16x8*)(ab + row * 128 + ((kk * 64 + lk16) ^ swz));
      }
#pragma unroll
      for (int n = 0; n < NREP; n++) {
        int row = wn * (BN / 4) + n * 16 + lr;
        bf[n] = *(const bf16x8*)(bb + row * 128 + ((kk * 64 + lk16) ^ swz));
      }
#pragma unroll
      for (int m = 0; m < MREP; m++)
#pragma unroll
        for (int n = 0; n < NREP; n++)
          acc[m][n] = mfma16(af[m], bf[n], acc[m][n]);
    }
  }
}

// ---------------------------------------------------------------------------
// Dual Q-projection: 256x128 tile, grid (8,16,2) = 256 blocks.
// ---------------------------------------------------------------------------
__global__ __launch_bounds__(512, 2) void gemm_q2(const unsigned short* __restrict__ A0,
                                                  const unsigned short* __restrict__ B0,
                                                  const float* __restrict__ bias0,
                                                  unsigned short* __restrict__ C0,
                                                  const unsigned short* __restrict__ A1,
                                                  const unsigned short* __restrict__ B1,
                                                  const float* __restrict__ bias1,
                                                  unsigned short* __restrict__ C1) {
  __shared__ unsigned short Al[2 * 256 * 64];  // 64KB
  __shared__ unsigned short Bl[2 * 128 * 64];  // 32KB
  int bn, bm, z;
  swz3(bn, bm, z);
  const unsigned short* A = z ? A1 : A0;
  const unsigned short* Bt = z ? B1 : B0;
  const float* bias = z ? bias1 : bias0;
  unsigned short* C = z ? C1 : C0;
  const int lane = threadIdx.x & 63, wave = threadIdx.x >> 6;
  const int lr = lane & 15, g4 = lane >> 4;
  const int wm = wave >> 2, wn = wave & 3;
  f32x4 acc[8][2];
  g256_main<256, 128, 8, 2>(A, Bt, 1024, bm, bn, Al, Bl, acc);
#pragma unroll
  for (int n = 0; n < 2; n++) {
    int col = bn * 128 + wn * 32 + n * 16 + lr;
    float bv = bias[col];
#pragma unroll
    for (int m = 0; m < 8; m++) {
      int row0 = bm * 256 + wm * 128 + m * 16 + g4 * 4;
#pragma unroll
      for (int r = 0; r < 4; r++)
        C[(size_t)(row0 + r) * 1024 + col] = f2bf(acc[m][n][r] + bv);
    }
  }
}

// ---------------------------------------------------------------------------
// Dual KV projection: 256x256 tile, grid (8,16,2) = 256 blocks.
// K half -> Kbuf [4096][1024]; V half -> V^T [bh][64 d][1024 s].
// ---------------------------------------------------------------------------
__global__ __launch_bounds__(512, 2) void gemm_kv2(const unsigned short* __restrict__ A0,
                                                   const unsigned short* __restrict__ B0,
                                                   const float* __restrict__ bias0,
                                                   unsigned short* __restrict__ K0,
                                                   unsigned short* __restrict__ V0,
                                                   const unsigned short* __restrict__ A1,
                                                   const unsigned short* __restrict__ B1,
                                                   const float* __restrict__ bias1,
                                                   unsigned short* __restrict__ K1,
                                                   unsigned short* __restrict__ V1) {
  __shared__ unsigned short Al[2 * 256 * 64];  // 64KB
  __shared__ unsigned short Bl[2 * 256 * 64];  // 64KB
  int bn, bm, z;
  swz3(bn, bm, z);
  const unsigned short* A = z ? A1 : A0;
  const unsigned short* Bt = z ? B1 : B0;
  const float* bias = z ? bias1 : bias0;
  unsigned short* Kbuf = z ? K1 : K0;
  unsigned short* VtG = z ? V1 : V0;
  const int lane = threadIdx.x & 63, wave = threadIdx.x >> 6;
  const int lr = lane & 15, g4 = lane >> 4;
  const int wm = wave >> 2, wn = wave & 3;
  f32x4 acc[8][4];
  g256_main<256, 256, 8, 4>(A, Bt, 1024, bm, bn, Al, Bl, acc);
#pragma unroll
  for (int n = 0; n < 4; n++) {
    int col = bn * 256 + wn * 64 + n * 16 + lr;
    float bv = bias[col];
#pragma unroll
    for (int m = 0; m < 8; m++) {
      int row0 = bm * 256 + wm * 128 + m * 16 + g4 * 4;
      if (col < 1024) {
#pragma unroll
        for (int r = 0; r < 4; r++)
          Kbuf[(size_t)(row0 + r) * 1024 + col] = f2bf(acc[m][n][r] + bv);
      } else {
        int h = (col - 1024) >> 6, d = (col - 1024) & 63;
        int b = row0 >> 10, s = row0 & 1023;
        ushort4 pk;
        pk.x = f2bf(acc[m][n][0] + bv);
        pk.y = f2bf(acc[m][n][1] + bv);
        pk.z = f2bf(acc[m][n][2] + bv);
        pk.w = f2bf(acc[m][n][3] + bv);
        *(ushort4*)&VtG[((size_t)(b * 16 + h) * 64 + d) * 1024 + s] = pk;
      }
    }
  }
}

// ---------------------------------------------------------------------------
// Output projection: fused[4096][2048] @ Wt_p^T + bp -> fp32 out.
// ---------------------------------------------------------------------------
__global__ __launch_bounds__(512, 4) void gemm_out(const unsigned short* __restrict__ A,
                                                   const unsigned short* __restrict__ Bt,
                                                   const float* __restrict__ bias,
                                                   float* __restrict__ C) {
  __shared__ unsigned short Al[2 * 128 * 64];  // 32KB
  __shared__ unsigned short Bl[2 * 128 * 64];  // 32KB
  int bn, bm, z;
  swz3(bn, bm, z);
  const int lane = threadIdx.x & 63, wave = threadIdx.x >> 6;
  const int lr = lane & 15, g4 = lane >> 4;
  const int wm = wave >> 2, wn = wave & 3;
  f32x4 acc[4][2];
  g256_main<128, 128, 4, 2>(A, Bt, 2048, bm, bn, Al, Bl, acc);
#pragma unroll
  for (int n = 0; n < 2; n++) {
    int col = bn * 128 + wn * 32 + n * 16 + lr;
    float bv = bias[col];
#pragma unroll
    for (int m = 0; m < 4; m++) {
      int row0 = bm * 128 + wm * 64 + m * 16 + g4 * 4;
#pragma unroll
      for (int r = 0; r < 4; r++)
        C[(size_t)(row0 + r) * 1024 + col] = acc[m][n][r] + bv;
    }
  }
  (void)z;
}

// ---------------------------------------------------------------------------
// Fused dual-direction flash attention, QBLK=128, KVBLK=64 (40KB LDS ->
// 4 blocks/CU). Double-buffered K/V staging in R8's proven issue order.
// Grid (16,64): qt=y&7, u=x+(y>>3)*16, dir=u>>6, bh=u&63; the 8 q-tiles of
// one (dir,bh) share an XCD (flat%8 = x%8, x fixed per u).
// ---------------------------------------------------------------------------
__global__ __launch_bounds__(256, 3) void attn_fused(const unsigned short* __restrict__ Qs,
                                                     const unsigned short* __restrict__ Ks,
                                                     const unsigned short* __restrict__ Vs,
                                                     const unsigned short* __restrict__ Qf,
                                                     const unsigned short* __restrict__ Kf,
                                                     const unsigned short* __restrict__ Vf,
                                                     unsigned short* __restrict__ Out) {
  __shared__ unsigned short Kl[2][64 * 64];   // 16KB dbuf K tile [key][d]
  __shared__ unsigned short Vt[2][64 * 64];   // 16KB dbuf V^T tile [d][key]
  __shared__ unsigned short Pl[4][16 * 64];   // 8KB per-wave P (reused per g)

  const int tid = threadIdx.x;
  const int wave = tid >> 6, lane = tid & 63;
  const int qt = blockIdx.y & 7;
  const int u = blockIdx.x + (blockIdx.y >> 3) * 16;
  const int dir = u >> 6, bh = u & 63;
  const int b = bh >> 4, h = bh & 15;
  const unsigned short* Q = dir ? Qf : Qs;
  const unsigned short* Kg = dir ? Kf : Ks;
  const unsigned short* VtG = dir ? Vf : Vs;
  const int outColBase = dir ? 1024 : 0;
  const float clo = dir ? -3.0e38f : -100.f;
  const float chi = dir ? 3.0e38f : 100.f;

  const int lr = lane & 15;
  const int lk16 = (lane >> 4) * 16;
  const int g4 = lane >> 4;

  // Q fragments in registers: 2 groups x 16 rows
  bf16x8 qa[2][2];
#pragma unroll
  for (int g = 0; g < 2; g++) {
    const size_t qrow = (size_t)b * 1024 + qt * 128 + wave * 32 + g * 16 + lr;
    const char* qp = (const char*)(Q + qrow * 1024 + h * 64);
    qa[g][0] = *(const bf16x8*)(qp + lk16);
    qa[g][1] = *(const bf16x8*)(qp + 64 + lk16);
  }

  f32x4 acc[2][4] = {};
  float mrun[2][4], lsum[2][4];
#pragma unroll
  for (int g = 0; g < 2; g++)
#pragma unroll
    for (int r = 0; r < 4; r++) { mrun[g][r] = -1e30f; lsum[g][r] = 0.f; }

  const char* kbase = (const char*)Kg + (size_t)b * 1024 * 2048 + h * 128;
  const char* vbase = (const char*)VtG + (size_t)bh * 64 * 2048;

  // stage 64-key tile kt (512 x 16B chunks, 2/thread), src pre-swizzled
  auto stage = [&](int buf, int kt) {
#pragma unroll
    for (int p2 = 0; p2 < 2; p2++) {
      int chunk = tid + p2 * 256;                  // 0..511
      int r = chunk >> 3, cb = (chunk & 7) * 16;   // key row 0..63, 16B col
      const char* src = kbase + (size_t)(kt * 64 + r) * 2048 + (cb ^ ((r & 7) << 4));
      char* dst = (char*)&Kl[buf][0] + (p2 * 256 + wave * 64) * 16;  // wave-uniform
      gld_lds16(src, dst);
    }
#pragma unroll
    for (int p2 = 0; p2 < 2; p2++) {
      int chunk = tid + p2 * 256;
      int d = chunk >> 3, ko = (chunk & 7) * 16;   // d row 0..63, 16B col
      const char* src = vbase + (size_t)d * 2048 + kt * 128 + (ko ^ ((d & 7) << 4));
      char* dst = (char*)&Vt[buf][0] + (p2 * 256 + wave * 64) * 16;  // wave-uniform
      gld_lds16(src, dst);
    }
  };

  char* pb = (char*)&Pl[wave][0];

  stage(0, 0);
  for (int kt = 0; kt < 16; ++kt) {
    __syncthreads();                 // stage(kt) complete; prev reads done
    if (kt < 15) stage((kt + 1) & 1, kt + 1);  // flies during compute(kt)
    const char* kb = (const char*)&Kl[kt & 1][0];
    const char* vb = (const char*)&Vt[kt & 1][0];

#pragma unroll
    for (int g = 0; g < 2; g++) {
      // QK^T: 16 q-rows x 64 keys
      f32x4 st[4];
#pragma unroll
      for (int t4 = 0; t4 < 4; t4++) {
        int krow = t4 * 16 + lr;
        int sw = (krow & 7) << 4;
        const char* kr = kb + krow * 128;
        bf16x8 kb0 = *(const bf16x8*)(kr + ((0 + lk16) ^ sw));
        bf16x8 kb1 = *(const bf16x8*)(kr + ((64 + lk16) ^ sw));
        f32x4 s = {};
        s = mfma16(qa[g][0], kb0, s);
        s = mfma16(qa[g][1], kb1, s);
#pragma unroll
        for (int r = 0; r < 4; r++)
          s[r] = fminf(fmaxf(s[r] * 0.125f, clo), chi);
        st[t4] = s;
      }

      // online softmax (rows g4*4+r; keys over 16-lane group + st[4])
#pragma unroll
      for (int r = 0; r < 4; r++) {
        float mx = fmaxf(fmaxf(st[0][r], st[1][r]), fmaxf(st[2][r], st[3][r]));
#pragma unroll
        for (int off = 1; off < 16; off <<= 1) mx = fmaxf(mx, __shfl_xor(mx, off, 64));
        float mnew = fmaxf(mrun[g][r], mx);
        float al = __expf(mrun[g][r] - mnew);
        float sum = 0.f;
#pragma unroll
        for (int t4 = 0; t4 < 4; t4++) {
          float pv = __expf(st[t4][r] - mnew);
          st[t4][r] = pv;
          sum += pv;
        }
#pragma unroll
        for (int off = 1; off < 16; off <<= 1) sum += __shfl_xor(sum, off, 64);
        lsum[g][r] = lsum[g][r] * al + sum;
        mrun[g][r] = mnew;
#pragma unroll
        for (int n = 0; n < 4; n++) acc[g][n][r] *= al;
      }

      // P -> per-wave LDS (swizzled, 128B rows); wave-local DS order -> safe reuse
#pragma unroll
      for (int t4 = 0; t4 < 4; t4++) {
        int key = t4 * 16 + lr;
#pragma unroll
        for (int r = 0; r < 4; r++) {
          int prow = g4 * 4 + r;
          *(unsigned short*)(pb + ((prow * 128 + key * 2) ^ ((prow & 7) << 4))) =
              f2bf(st[t4][r]);
        }
      }

      // PV: O += P[16x64] @ V[64x64]
      bf16x8 pa[2];
#pragma unroll
      for (int kc = 0; kc < 2; kc++)
        pa[kc] = *(const bf16x8*)(pb + ((lr * 128 + kc * 64 + lk16) ^ ((lr & 7) << 4)));
#pragma unroll
      for (int n = 0; n < 4; n++) {
        int vr = n * 16 + lr;
        int sw = (vr & 7) << 4;
        const char* vp = vb + vr * 128;
#pragma unroll
        for (int kc = 0; kc < 2; kc++) {
          bf16x8 vbv = *(const bf16x8*)(vp + ((kc * 64 + lk16) ^ sw));
          acc[g][n] = mfma16(pa[kc], vbv, acc[g][n]);
        }
      }
    }
  }

  // epilogue: O / l -> bf16 fused
#pragma unroll
  for (int g = 0; g < 2; g++) {
    const size_t orow0 = (size_t)b * 1024 + qt * 128 + wave * 32 + g * 16 + g4 * 4;
#pragma unroll
    for (int n = 0; n < 4; n++) {
      int col = outColBase + h * 64 + n * 16 + lr;
#pragma unroll
      for (int r = 0; r < 4; r++) {
        float o = acc[g][n][r] / lsum[g][r];
        Out[(orow0 + r) * 2048 + col] = f2bf(o);
      }
    }
  }
}

// ---------------------------------------------------------------------------
// In-place LayerNorm over rows of 1024 fp32 (1 block = 1 row, 256 thr)
// ---------------------------------------------------------------------------
__global__ __launch_bounds__(256) void ln_inplace(float* __restrict__ io,
                                                  const float* __restrict__ gamma,
                                                  const float* __restrict__ beta) {
  __shared__ float red[8];
  int row = blockIdx.x, tid = threadIdx.x;
  float* p = io + (size_t)row * 1024;
  float4 x = ((const float4*)p)[tid];
  float s = x.x + x.y + x.z + x.w;
  float s2 = x.x * x.x + x.y * x.y + x.z * x.z + x.w * x.w;
#pragma unroll
  for (int off = 32; off; off >>= 1) {
    s += __shfl_down(s, off, 64);
    s2 += __shfl_down(s2, off, 64);
  }
  int wv = tid >> 6;
  if ((tid & 63) == 0) { red[wv] = s; red[4 + wv] = s2; }
  __syncthreads();
  if (tid == 0) {
    red[0] = red[0] + red[1] + red[2] + red[3];
    red[4] = red[4] + red[5] + red[6] + red[7];
  }
  __syncthreads();
  float mu = red[0] * (1.f / 1024.f);
  float var = red[4] * (1.f / 1024.f) - mu * mu;
  float inv = rsqrtf(var + 1e-5f);
  float4 g = ((const float4*)gamma)[tid];
  float4 bb = ((const float4*)beta)[tid];
  x.x = (x.x - mu) * inv * g.x + bb.x;
  x.y = (x.y - mu) * inv * g.y + bb.y;
  x.z = (x.z - mu) * inv * g.z + bb.z;
  x.w = (x.w - mu) * inv * g.w + bb.w;
  ((float4*)p)[tid] = x;
}

// ---------------------------------------------------------------------------
extern "C" void kernel_launch(void* const* d_in, const int* in_sizes, int n_in,
                              void* d_out, int out_size, void* d_ws, size_t ws_size,
                              hipStream_t stream) {
  (void)in_sizes; (void)n_in; (void)out_size; (void)ws_size;
  const float* image = (const float*)d_in[0];
  const float* wavef = (const float*)d_in[1];
  const float* Wq_i  = (const float*)d_in[2];
  const float* bq_i  = (const float*)d_in[3];
  const float* Wkv_w = (const float*)d_in[4];
  const float* bkv_w = (const float*)d_in[5];
  const float* Wq_w  = (const float*)d_in[6];
  const float* bq_w  = (const float*)d_in[7];
  const float* Wkv_i = (const float*)d_in[8];
  const float* bkv_i = (const float*)d_in[9];
  const float* Wp    = (const float*)d_in[10];
  const float* bp    = (const float*)d_in[11];
  const float* gamma = (const float*)d_in[12];
  const float* beta  = (const float*)d_in[13];
  float* out = (float*)d_out;

  char* ws = (char*)d_ws;
  unsigned short* Xi = (unsigned short*)ws;                       // 8 MiB
  unsigned short* Xw = (unsigned short*)ws + 4096ull * 1024;      // 8 MiB
  unsigned short* fused = (unsigned short*)ws;                    // 16 MiB alias
  size_t off = 16ull << 20;
  auto take = [&](size_t bytes) { void* p = ws + off; off += bytes; return p; };
  unsigned short* Wt_qi  = (unsigned short*)take(2ull << 20);
  unsigned short* Wt_kvw = (unsigned short*)take(4ull << 20);
  unsigned short* Wt_qw  = (unsigned short*)take(2ull << 20);
  unsigned short* Wt_kvi = (unsigned short*)take(4ull << 20);
  unsigned short* Wt_p   = (unsigned short*)take(4ull << 20);
  unsigned short* q_s    = (unsigned short*)take(8ull << 20);
  unsigned short* q_f    = (unsigned short*)take(8ull << 20);
  unsigned short* kvK_w  = (unsigned short*)take(8ull << 20);
  unsigned short* VtG_w  = (unsigned short*)take(8ull << 20);
  unsigned short* kvK_s  = (unsigned short*)take(8ull << 20);
  unsigned short* VtG_s  = (unsigned short*)take(8ull << 20);

  // 1) convert both activations to bf16
  cvt2_kernel<<<8192, 256, 0, stream>>>(image, Xi, wavef, Xw);
  // 2) all 5 weight transposes
  TransArgs ta;
  ta.W[0] = Wq_i;  ta.Wt[0] = Wt_qi;
  ta.W[1] = Wkv_w; ta.Wt[1] = Wt_kvw;
  ta.W[2] = Wq_w;  ta.Wt[2] = Wt_qw;
  ta.W[3] = Wkv_i; ta.Wt[3] = Wt_kvi;
  ta.W[4] = Wp;    ta.Wt[4] = Wt_p;
  transpose_all<<<8192, 256, 0, stream>>>(ta);
  // 3) projections (8-wave big-tile, swizzled LDS)
  gemm_q2<<<dim3(8, 16, 2), 512, 0, stream>>>(Xi, Wt_qi, bq_i, q_s,
                                              Xw, Wt_qw, bq_w, q_f);
  gemm_kv2<<<dim3(8, 16, 2), 512, 0, stream>>>(Xw, Wt_kvw, bkv_w, kvK_w, VtG_w,
                                               Xi, Wt_kvi, bkv_i, kvK_s, VtG_s);
  // 4) fused dual-direction cross attention (KVBLK=64, 4 blocks/CU)
  attn_fused<<<dim3(16, 64), 256, 0, stream>>>(q_s, kvK_w, VtG_w,
                                               q_f, kvK_s, VtG_s, fused);
  // 5) output projection + 6) LayerNorm
  gemm_out<<<dim3(8, 32), 512, 0, stream>>>(fused, Wt_p, bp, out);
  ln_inplace<<<4096, 256, 0, stream>>>(out, gamma, beta);
}

// Round 13
// 223.912 us; speedup vs baseline: 1.2029x; 1.2029x over previous
//
#include <hip/hip_runtime.h>
#include <hip/hip_bf16.h>

#define DEVINL __device__ __forceinline__

typedef float f32x4 __attribute__((ext_vector_type(4)));
typedef __bf16 bf16x8 __attribute__((ext_vector_type(8)));

DEVINL void gld_lds16(const void* g, void* l) {
  __builtin_amdgcn_global_load_lds(
      (const __attribute__((address_space(1))) unsigned int*)g,
      (__attribute__((address_space(3))) unsigned int*)l, 16, 0, 0);
}

DEVINL unsigned short f2bf(float f) {
  __bf16 h = (__bf16)f;
  return __builtin_bit_cast(unsigned short, h);
}

DEVINL f32x4 mfma16(bf16x8 a, bf16x8 b, f32x4 c) {
  return __builtin_amdgcn_mfma_f32_16x16x32_bf16(a, b, c, 0, 0, 0);
}

// XCD-aware bijective block remap (nwg divisible by 8).
DEVINL void swz3(int& bn, int& bm, int& z) {
  int gx = gridDim.x, gy = gridDim.y;
  int nwg = gx * gy * gridDim.z;
  int flat = blockIdx.x + gx * (blockIdx.y + gy * blockIdx.z);
  int wg = (flat & 7) * (nwg >> 3) + (flat >> 3);
  bn = wg % gx;
  int t = wg / gx;
  bm = t % gy;
  z = t / gy;
}

// ---------------------------------------------------------------------------
// fp32 -> bf16 convert, both activations in one launch (grid 8192 x 256)
// ---------------------------------------------------------------------------
__global__ __launch_bounds__(256) void cvt2_kernel(const float* __restrict__ inA,
                                                   unsigned short* __restrict__ outA,
                                                   const float* __restrict__ inB,
                                                   unsigned short* __restrict__ outB) {
  int bx = blockIdx.x;
  const float* in = bx < 4096 ? inA : inB;
  unsigned short* outp = bx < 4096 ? outA : outB;
  int i = (bx & 4095) * 256 + threadIdx.x;
  float4 v = ((const float4*)in)[i];
  ushort4 o;
  o.x = f2bf(v.x); o.y = f2bf(v.y); o.z = f2bf(v.z); o.w = f2bf(v.w);
  ((ushort4*)outp)[i] = o;
}

// ---------------------------------------------------------------------------
// All 5 weight transposes (W[K][N] fp32 -> Wt[N][K] bf16) in one launch.
// ---------------------------------------------------------------------------
struct TransArgs {
  const float* W[5];
  unsigned short* Wt[5];
};

DEVINL void trans_tile(const float* W, unsigned short* Wt, int K, int N,
                       int xt, int yt) {
  __shared__ float t[32][33];
  int n0 = xt * 32, k0 = yt * 32;
  int tx = threadIdx.x & 31, ty = threadIdx.x >> 5;  // ty 0..7
#pragma unroll
  for (int i = 0; i < 4; i++)
    t[ty + i * 8][tx] = W[(size_t)(k0 + ty + i * 8) * N + n0 + tx];
  __syncthreads();
#pragma unroll
  for (int i = 0; i < 4; i++) {
    int n = ty + i * 8;
    Wt[(size_t)(n0 + n) * K + k0 + tx] = f2bf(t[tx][n]);
  }
}

__global__ __launch_bounds__(256) void transpose_all(TransArgs a) {
  int t = blockIdx.x;
  if (t < 1024)       trans_tile(a.W[0], a.Wt[0], 1024, 1024, t % 32, t / 32);
  else if (t < 3072)  { int l = t - 1024; trans_tile(a.W[1], a.Wt[1], 1024, 2048, l % 64, l / 64); }
  else if (t < 4096)  { int l = t - 3072; trans_tile(a.W[2], a.Wt[2], 1024, 1024, l % 32, l / 32); }
  else if (t < 6144)  { int l = t - 4096; trans_tile(a.W[3], a.Wt[3], 1024, 2048, l % 64, l / 64); }
  else                { int l = t - 6144; trans_tile(a.W[4], a.Wt[4], 2048, 1024, l % 32, l / 32); }
}

// ---------------------------------------------------------------------------
// 8-wave GEMM main loop (BM x BN tile, BK=64, 512 threads, waves 2M x 4N).
// T2 XOR swizzle; double-buffered, one barrier per K-step (m97 order).
// ---------------------------------------------------------------------------
template <int BM, int BN, int MREP, int NREP>
DEVINL void g256_main(const unsigned short* A, const unsigned short* Bt, int K,
                      int bm, int bn, unsigned short* Al, unsigned short* Bl,
                      f32x4 (&acc)[MREP][NREP]) {
  const int tid = threadIdx.x;
  const int wave = tid >> 6, lane = tid & 63;
  const int lr = lane & 15;
  const int lk16 = (lane >> 4) * 16;
  const int wm = wave >> 2, wn = wave & 3;
  const int swz = (lr & 7) << 4;
  const int nk = K >> 6;
  const size_t Kb = (size_t)K * 2;

#pragma unroll
  for (int m = 0; m < MREP; m++)
#pragma unroll
    for (int n = 0; n < NREP; n++) acc[m][n] = f32x4{0.f, 0.f, 0.f, 0.f};

  auto stage = [&](int buf, int kt) {
#pragma unroll
    for (int i = 0; i < BM / 64; i++) {
      int chunk = i * 512 + tid;
      int row = chunk >> 3, cb = (chunk & 7) * 16;
      const char* src = (const char*)A + (size_t)(bm * BM + row) * Kb +
                        kt * 128 + (cb ^ ((row & 7) << 4));
      char* dst = (char*)(Al + (size_t)buf * BM * 64) + (i * 512 + wave * 64) * 16;
      gld_lds16(src, dst);
    }
#pragma unroll
    for (int i = 0; i < BN / 64; i++) {
      int chunk = i * 512 + tid;
      int row = chunk >> 3, cb = (chunk & 7) * 16;
      const char* src = (const char*)Bt + (size_t)(bn * BN + row) * Kb +
                        kt * 128 + (cb ^ ((row & 7) << 4));
      char* dst = (char*)(Bl + (size_t)buf * BN * 64) + (i * 512 + wave * 64) * 16;
      gld_lds16(src, dst);
    }
  };

  stage(0, 0);
  for (int kt = 0; kt < nk; ++kt) {
    __syncthreads();
    if (kt + 1 < nk) stage((kt + 1) & 1, kt + 1);
    const char* ab = (const char*)(Al + (size_t)(kt & 1) * BM * 64);
    const char* bb = (const char*)(Bl + (size_t)(kt & 1) * BN * 64);
#pragma unroll
    for (int kk = 0; kk < 2; kk++) {
      bf16x8 af[MREP], bf[NREP];
#pragma unroll
      for (int m = 0; m < MREP; m++) {
        int row = wm * (BM / 2) + m * 16 + lr;
        af[m] = *(const bf16x8*)(ab + row * 128 + ((kk * 64 + lk16) ^ swz));
      }
#pragma unroll
      for (int n = 0; n < NREP; n++) {
        int row = wn * (BN / 4) + n * 16 + lr;
        bf[n] = *(const bf16x8*)(bb + row * 128 + ((kk * 64 + lk16) ^ swz));
      }
#pragma unroll
      for (int m = 0; m < MREP; m++)
#pragma unroll
        for (int n = 0; n < NREP; n++)
          acc[m][n] = mfma16(af[m], bf[n], acc[m][n]);
    }
  }
}

// ---------------------------------------------------------------------------
// Dual Q-projection: 256x128 tile, grid (8,16,2) = 256 blocks.
// ---------------------------------------------------------------------------
__global__ __launch_bounds__(512, 2) void gemm_q2(const unsigned short* __restrict__ A0,
                                                  const unsigned short* __restrict__ B0,
                                                  const float* __restrict__ bias0,
                                                  unsigned short* __restrict__ C0,
                                                  const unsigned short* __restrict__ A1,
                                                  const unsigned short* __restrict__ B1,
                                                  const float* __restrict__ bias1,
                                                  unsigned short* __restrict__ C1) {
  __shared__ unsigned short Al[2 * 256 * 64];  // 64KB
  __shared__ unsigned short Bl[2 * 128 * 64];  // 32KB
  int bn, bm, z;
  swz3(bn, bm, z);
  const unsigned short* A = z ? A1 : A0;
  const unsigned short* Bt = z ? B1 : B0;
  const float* bias = z ? bias1 : bias0;
  unsigned short* C = z ? C1 : C0;
  const int lane = threadIdx.x & 63, wave = threadIdx.x >> 6;
  const int lr = lane & 15, g4 = lane >> 4;
  const int wm = wave >> 2, wn = wave & 3;
  f32x4 acc[8][2];
  g256_main<256, 128, 8, 2>(A, Bt, 1024, bm, bn, Al, Bl, acc);
#pragma unroll
  for (int n = 0; n < 2; n++) {
    int col = bn * 128 + wn * 32 + n * 16 + lr;
    float bv = bias[col];
#pragma unroll
    for (int m = 0; m < 8; m++) {
      int row0 = bm * 256 + wm * 128 + m * 16 + g4 * 4;
#pragma unroll
      for (int r = 0; r < 4; r++)
        C[(size_t)(row0 + r) * 1024 + col] = f2bf(acc[m][n][r] + bv);
    }
  }
}

// ---------------------------------------------------------------------------
// Dual KV projection: 256x256 tile, grid (8,16,2) = 256 blocks.
// K half -> Kbuf [4096][1024]; V half -> V^T [bh][64 d][1024 s].
// ---------------------------------------------------------------------------
__global__ __launch_bounds__(512, 2) void gemm_kv2(const unsigned short* __restrict__ A0,
                                                   const unsigned short* __restrict__ B0,
                                                   const float* __restrict__ bias0,
                                                   unsigned short* __restrict__ K0,
                                                   unsigned short* __restrict__ V0,
                                                   const unsigned short* __restrict__ A1,
                                                   const unsigned short* __restrict__ B1,
                                                   const float* __restrict__ bias1,
                                                   unsigned short* __restrict__ K1,
                                                   unsigned short* __restrict__ V1) {
  __shared__ unsigned short Al[2 * 256 * 64];  // 64KB
  __shared__ unsigned short Bl[2 * 256 * 64];  // 64KB
  int bn, bm, z;
  swz3(bn, bm, z);
  const unsigned short* A = z ? A1 : A0;
  const unsigned short* Bt = z ? B1 : B0;
  const float* bias = z ? bias1 : bias0;
  unsigned short* Kbuf = z ? K1 : K0;
  unsigned short* VtG = z ? V1 : V0;
  const int lane = threadIdx.x & 63, wave = threadIdx.x >> 6;
  const int lr = lane & 15, g4 = lane >> 4;
  const int wm = wave >> 2, wn = wave & 3;
  f32x4 acc[8][4];
  g256_main<256, 256, 8, 4>(A, Bt, 1024, bm, bn, Al, Bl, acc);
#pragma unroll
  for (int n = 0; n < 4; n++) {
    int col = bn * 256 + wn * 64 + n * 16 + lr;
    float bv = bias[col];
#pragma unroll
    for (int m = 0; m < 8; m++) {
      int row0 = bm * 256 + wm * 128 + m * 16 + g4 * 4;
      if (col < 1024) {
#pragma unroll
        for (int r = 0; r < 4; r++)
          Kbuf[(size_t)(row0 + r) * 1024 + col] = f2bf(acc[m][n][r] + bv);
      } else {
        int h = (col - 1024) >> 6, d = (col - 1024) & 63;
        int b = row0 >> 10, s = row0 & 1023;
        ushort4 pk;
        pk.x = f2bf(acc[m][n][0] + bv);
        pk.y = f2bf(acc[m][n][1] + bv);
        pk.z = f2bf(acc[m][n][2] + bv);
        pk.w = f2bf(acc[m][n][3] + bv);
        *(ushort4*)&VtG[((size_t)(b * 16 + h) * 64 + d) * 1024 + s] = pk;
      }
    }
  }
}

// ---------------------------------------------------------------------------
// Output projection: fused[4096][2048] @ Wt_p^T + bp -> fp32 out.
// ---------------------------------------------------------------------------
__global__ __launch_bounds__(512, 4) void gemm_out(const unsigned short* __restrict__ A,
                                                   const unsigned short* __restrict__ Bt,
                                                   const float* __restrict__ bias,
                                                   float* __restrict__ C) {
  __shared__ unsigned short Al[2 * 128 * 64];  // 32KB
  __shared__ unsigned short Bl[2 * 128 * 64];  // 32KB
  int bn, bm, z;
  swz3(bn, bm, z);
  const int lane = threadIdx.x & 63, wave = threadIdx.x >> 6;
  const int lr = lane & 15, g4 = lane >> 4;
  const int wm = wave >> 2, wn = wave & 3;
  f32x4 acc[4][2];
  g256_main<128, 128, 4, 2>(A, Bt, 2048, bm, bn, Al, Bl, acc);
#pragma unroll
  for (int n = 0; n < 2; n++) {
    int col = bn * 128 + wn * 32 + n * 16 + lr;
    float bv = bias[col];
#pragma unroll
    for (int m = 0; m < 4; m++) {
      int row0 = bm * 128 + wm * 64 + m * 16 + g4 * 4;
#pragma unroll
      for (int r = 0; r < 4; r++)
        C[(size_t)(row0 + r) * 1024 + col] = acc[m][n][r] + bv;
    }
  }
  (void)z;
}

// ---------------------------------------------------------------------------
// Flash attention, QBLK=128, KVBLK=128, double-buffered K/V staging (R10),
// SWAPPED-QK IN-REGISTER SOFTMAX (lane algebra HW-verified in R7): each lane
// owns one q-row's 32 scores per tile -> row reduce = local tree + 2 shfl;
// P redistributed to PV A-fragments via shfl (no P LDS). LDS 64KB.
// Grid (8,64): all 8 q-tiles of one (b,h) share an XCD.
// ---------------------------------------------------------------------------
template <bool CLAMP>
__global__ __launch_bounds__(256, 2) void attn_kernel(const unsigned short* __restrict__ Q,
                                                      const unsigned short* __restrict__ Kg,
                                                      const unsigned short* __restrict__ VtG,
                                                      unsigned short* __restrict__ Out,
                                                      int outColBase) {
  __shared__ unsigned short Kl[2][128 * 64];  // 32KB dbuf K tile [key][d]
  __shared__ unsigned short Vt[2][64 * 128];  // 32KB dbuf V^T tile [d][key]

  const int tid = threadIdx.x;
  const int wave = tid >> 6, lane = tid & 63;
  const int qt = blockIdx.y & 7;
  const int bh = blockIdx.x * 8 + (blockIdx.y >> 3);
  const int b = bh >> 4, h = bh & 15;
  const int q16 = lane & 15;       // this lane's q-row (softmax) & output col
  const int g4 = lane >> 4;        // key-quarter group
  const int lk16 = g4 * 16;

  // Q fragments (B-operand): lane holds Q[q16][d-chunk g4*8..]
  bf16x8 qa[2][2];
#pragma unroll
  for (int g = 0; g < 2; g++) {
    const size_t qrow = (size_t)b * 1024 + qt * 128 + wave * 32 + g * 16 + q16;
    const char* qp = (const char*)(Q + qrow * 1024 + h * 64);
    qa[g][0] = *(const bf16x8*)(qp + lk16);
    qa[g][1] = *(const bf16x8*)(qp + 64 + lk16);
  }

  f32x4 acc[2][4] = {};
  float mrun[2] = {-1e30f, -1e30f}, lsum[2] = {0.f, 0.f};

  const char* kbase = (const char*)Kg + (size_t)b * 1024 * 2048 + h * 128;
  const char* vbase = (const char*)VtG + (size_t)bh * 64 * 2048;

  // stage tile kt into buffer buf (src pre-swizzled; LDS dest linear) — R10
  auto stage = [&](int buf, int kt) {
#pragma unroll
    for (int p2 = 0; p2 < 4; p2++) {
      int chunk = tid + p2 * 256;                  // 0..1023
      int r = chunk >> 3, cb = (chunk & 7) * 16;   // key row, 16B col
      const char* src = kbase + (size_t)(kt * 128 + r) * 2048 + (cb ^ ((r & 7) << 4));
      char* dst = (char*)&Kl[buf][0] + (p2 * 256 + wave * 64) * 16;  // wave-uniform
      gld_lds16(src, dst);
    }
#pragma unroll
    for (int p2 = 0; p2 < 4; p2++) {
      int chunk = tid + p2 * 256;
      int d = chunk >> 4, ko = (chunk & 15) * 16;
      const char* src = vbase + (size_t)d * 2048 + kt * 256 + (ko ^ ((d & 7) << 4));
      char* dst = (char*)&Vt[buf][0] + (p2 * 256 + wave * 64) * 16;  // wave-uniform
      gld_lds16(src, dst);
    }
  };

  stage(0, 0);
  for (int kt = 0; kt < 8; ++kt) {
    __syncthreads();                 // stage(kt) complete; prev reads done
    if (kt < 7) stage((kt + 1) & 1, kt + 1);  // flies during compute(kt)
    const char* kb = (const char*)&Kl[kt & 1][0];
    const char* vb = (const char*)&Vt[kt & 1][0];

#pragma unroll
    for (int g = 0; g < 2; g++) {
      // swapped QK^T: st[t8][r] = S[key = t8*16 + 4*g4 + r][q16]
      f32x4 st[8];
#pragma unroll
      for (int t8 = 0; t8 < 8; t8++) {
        int krow = t8 * 16 + q16;
        int sw = (krow & 7) << 4;
        const char* kr = kb + krow * 128;
        bf16x8 kb0 = *(const bf16x8*)(kr + ((0 + lk16) ^ sw));
        bf16x8 kb1 = *(const bf16x8*)(kr + ((64 + lk16) ^ sw));
        f32x4 s = {};
        s = mfma16(kb0, qa[g][0], s);   // K as A, Q as B -> D[key][q]
        s = mfma16(kb1, qa[g][1], s);
#pragma unroll
        for (int r = 0; r < 4; r++) {
          float v = s[r] * 0.125f;
          if (CLAMP) v = fminf(fmaxf(v, -100.f), 100.f);
          s[r] = v;
        }
        st[t8] = s;
      }

      // row-softmax for q=q16: local tree + 2 shfl (lanes l, l^16, l^32, l^48)
      float tmax[8];
#pragma unroll
      for (int t8 = 0; t8 < 8; t8++)
        tmax[t8] = fmaxf(fmaxf(st[t8][0], st[t8][1]), fmaxf(st[t8][2], st[t8][3]));
      float mx = fmaxf(fmaxf(fmaxf(tmax[0], tmax[1]), fmaxf(tmax[2], tmax[3])),
                       fmaxf(fmaxf(tmax[4], tmax[5]), fmaxf(tmax[6], tmax[7])));
      mx = fmaxf(mx, __shfl_xor(mx, 16, 64));
      mx = fmaxf(mx, __shfl_xor(mx, 32, 64));
      float mnew = fmaxf(mrun[g], mx);
      float al = __expf(mrun[g] - mnew);
      mrun[g] = mnew;
      float sum = 0.f;
#pragma unroll
      for (int t8 = 0; t8 < 8; t8++) {
#pragma unroll
        for (int r = 0; r < 4; r++) {
          float pv = __expf(st[t8][r] - mnew);
          st[t8][r] = pv;
          sum += pv;
        }
      }
      sum += __shfl_xor(sum, 16, 64);
      sum += __shfl_xor(sum, 32, 64);
      lsum[g] = lsum[g] * al + sum;

      // rescale acc rows (acc row q = 4*g4+r; al lives in lanes with l&15==q)
      float alr[4];
#pragma unroll
      for (int r = 0; r < 4; r++) alr[r] = __shfl(al, 4 * g4 + r, 64);
#pragma unroll
      for (int n = 0; n < 4; n++)
#pragma unroll
        for (int r = 0; r < 4; r++) acc[g][n][r] *= alr[r];

      // pack P to bf16 pairs: plo[t8]=(r0,r1), phi[t8]=(r2,r3)
      unsigned int plo[8], phi[8];
#pragma unroll
      for (int t8 = 0; t8 < 8; t8++) {
        plo[t8] = ((unsigned)f2bf(st[t8][1]) << 16) | f2bf(st[t8][0]);
        phi[t8] = ((unsigned)f2bf(st[t8][3]) << 16) | f2bf(st[t8][2]);
      }

      // redistribute (R7, HW-verified): lane needs P[q16][keys kc*32+8*g4+0..7]
      // sources: s0 = q16 + 32*(g4&1) (j0..3), s1 = s0+16 (j4..7);
      // tile t8 = 2*kc + (g4>>1) -> shuffle both parities, select by g4>>1.
      const int s0 = q16 + ((g4 & 1) << 5);
      const int s1 = s0 + 16;
      const bool odd = (g4 & 2) != 0;
      bf16x8 pa[4];
#pragma unroll
      for (int kc = 0; kc < 4; kc++) {
        unsigned ae = __shfl(plo[2 * kc], s0, 64), be = __shfl(phi[2 * kc], s0, 64);
        unsigned ao = __shfl(plo[2 * kc + 1], s0, 64), bo = __shfl(phi[2 * kc + 1], s0, 64);
        unsigned ce = __shfl(plo[2 * kc], s1, 64), de = __shfl(phi[2 * kc], s1, 64);
        unsigned co = __shfl(plo[2 * kc + 1], s1, 64), dd = __shfl(phi[2 * kc + 1], s1, 64);
        uint4 w;
        w.x = odd ? ao : ae;
        w.y = odd ? bo : be;
        w.z = odd ? co : ce;
        w.w = odd ? dd : de;
        pa[kc] = __builtin_bit_cast(bf16x8, w);
      }

      // PV: O += P[16x128] @ V[128x64] (V from LDS, R10's verified reads)
#pragma unroll
      for (int n = 0; n < 4; n++) {
        int vr = n * 16 + q16;
        int sw = (vr & 7) << 4;
        const char* vp = vb + vr * 256;
#pragma unroll
        for (int kc = 0; kc < 4; kc++) {
          bf16x8 vbv = *(const bf16x8*)(vp + ((kc * 64 + lk16) ^ sw));
          acc[g][n] = mfma16(pa[kc], vbv, acc[g][n]);
        }
      }
    }
  }

  // epilogue: O / l -> bf16 fused (lsum lives in lanes with l&15==q -> shfl)
#pragma unroll
  for (int g = 0; g < 2; g++) {
    float lr4[4];
#pragma unroll
    for (int r = 0; r < 4; r++) lr4[r] = __shfl(lsum[g], 4 * g4 + r, 64);
    const size_t orow0 = (size_t)b * 1024 + qt * 128 + wave * 32 + g * 16 + g4 * 4;
#pragma unroll
    for (int n = 0; n < 4; n++) {
      int col = outColBase + h * 64 + n * 16 + q16;
#pragma unroll
      for (int r = 0; r < 4; r++) {
        float o = acc[g][n][r] / lr4[r];
        Out[(orow0 + r) * 2048 + col] = f2bf(o);
      }
    }
  }
}

// ---------------------------------------------------------------------------
// In-place LayerNorm over rows of 1024 fp32 (1 block = 1 row, 256 thr)
// ---------------------------------------------------------------------------
__global__ __launch_bounds__(256) void ln_inplace(float* __restrict__ io,
                                                  const float* __restrict__ gamma,
                                                  const float* __restrict__ beta) {
  __shared__ float red[8];
  int row = blockIdx.x, tid = threadIdx.x;
  float* p = io + (size_t)row * 1024;
  float4 x = ((const float4*)p)[tid];
  float s = x.x + x.y + x.z + x.w;
  float s2 = x.x * x.x + x.y * x.y + x.z * x.z + x.w * x.w;
#pragma unroll
  for (int off = 32; off; off >>= 1) {
    s += __shfl_down(s, off, 64);
    s2 += __shfl_down(s2, off, 64);
  }
  int wv = tid >> 6;
  if ((tid & 63) == 0) { red[wv] = s; red[4 + wv] = s2; }
  __syncthreads();
  if (tid == 0) {
    red[0] = red[0] + red[1] + red[2] + red[3];
    red[4] = red[4] + red[5] + red[6] + red[7];
  }
  __syncthreads();
  float mu = red[0] * (1.f / 1024.f);
  float var = red[4] * (1.f / 1024.f) - mu * mu;
  float inv = rsqrtf(var + 1e-5f);
  float4 g = ((const float4*)gamma)[tid];
  float4 bb = ((const float4*)beta)[tid];
  x.x = (x.x - mu) * inv * g.x + bb.x;
  x.y = (x.y - mu) * inv * g.y + bb.y;
  x.z = (x.z - mu) * inv * g.z + bb.z;
  x.w = (x.w - mu) * inv * g.w + bb.w;
  ((float4*)p)[tid] = x;
}

// ---------------------------------------------------------------------------
extern "C" void kernel_launch(void* const* d_in, const int* in_sizes, int n_in,
                              void* d_out, int out_size, void* d_ws, size_t ws_size,
                              hipStream_t stream) {
  (void)in_sizes; (void)n_in; (void)out_size; (void)ws_size;
  const float* image = (const float*)d_in[0];
  const float* wavef = (const float*)d_in[1];
  const float* Wq_i  = (const float*)d_in[2];
  const float* bq_i  = (const float*)d_in[3];
  const float* Wkv_w = (const float*)d_in[4];
  const float* bkv_w = (const float*)d_in[5];
  const float* Wq_w  = (const float*)d_in[6];
  const float* bq_w  = (const float*)d_in[7];
  const float* Wkv_i = (const float*)d_in[8];
  const float* bkv_i = (const float*)d_in[9];
  const float* Wp    = (const float*)d_in[10];
  const float* bp    = (const float*)d_in[11];
  const float* gamma = (const float*)d_in[12];
  const float* beta  = (const float*)d_in[13];
  float* out = (float*)d_out;

  char* ws = (char*)d_ws;
  unsigned short* Xi = (unsigned short*)ws;                       // 8 MiB
  unsigned short* Xw = (unsigned short*)ws + 4096ull * 1024;      // 8 MiB
  unsigned short* fused = (unsigned short*)ws;                    // 16 MiB alias
  size_t off = 16ull << 20;
  auto take = [&](size_t bytes) { void* p = ws + off; off += bytes; return p; };
  unsigned short* Wt_qi  = (unsigned short*)take(2ull << 20);
  unsigned short* Wt_kvw = (unsigned short*)take(4ull << 20);
  unsigned short* Wt_qw  = (unsigned short*)take(2ull << 20);
  unsigned short* Wt_kvi = (unsigned short*)take(4ull << 20);
  unsigned short* Wt_p   = (unsigned short*)take(4ull << 20);
  unsigned short* q_s    = (unsigned short*)take(8ull << 20);
  unsigned short* q_f    = (unsigned short*)take(8ull << 20);
  unsigned short* kvK_w  = (unsigned short*)take(8ull << 20);
  unsigned short* VtG_w  = (unsigned short*)take(8ull << 20);
  unsigned short* kvK_s  = (unsigned short*)take(8ull << 20);
  unsigned short* VtG_s  = (unsigned short*)take(8ull << 20);

  // 1) convert both activations to bf16
  cvt2_kernel<<<8192, 256, 0, stream>>>(image, Xi, wavef, Xw);
  // 2) all 5 weight transposes
  TransArgs ta;
  ta.W[0] = Wq_i;  ta.Wt[0] = Wt_qi;
  ta.W[1] = Wkv_w; ta.Wt[1] = Wt_kvw;
  ta.W[2] = Wq_w;  ta.Wt[2] = Wt_qw;
  ta.W[3] = Wkv_i; ta.Wt[3] = Wt_kvi;
  ta.W[4] = Wp;    ta.Wt[4] = Wt_p;
  transpose_all<<<8192, 256, 0, stream>>>(ta);
  // 3) projections (8-wave big-tile, swizzled LDS)
  gemm_q2<<<dim3(8, 16, 2), 512, 0, stream>>>(Xi, Wt_qi, bq_i, q_s,
                                              Xw, Wt_qw, bq_w, q_f);
  gemm_kv2<<<dim3(8, 16, 2), 512, 0, stream>>>(Xw, Wt_kvw, bkv_w, kvK_w, VtG_w,
                                               Xi, Wt_kvi, bkv_i, kvK_s, VtG_s);
  // 4) cross attention, KVBLK=128 split, in-register softmax
  attn_kernel<true ><<<dim3(8, 64), 256, 0, stream>>>(q_s, kvK_w, VtG_w, fused, 0);
  attn_kernel<false><<<dim3(8, 64), 256, 0, stream>>>(q_f, kvK_s, VtG_s, fused, 1024);
  // 5) output projection + 6) LayerNorm
  gemm_out<<<dim3(8, 32), 512, 0, stream>>>(fused, Wt_p, bp, out);
  ln_inplace<<<4096, 256, 0, stream>>>(out, gamma, beta);
}

// Round 16
// 215.329 us; speedup vs baseline: 1.2509x; 1.0399x over previous
//
#include <hip/hip_runtime.h>
#include <hip/hip_bf16.h>

#define DEVINL __device__ __forceinline__

typedef float f32x4 __attribute__((ext_vector_type(4)));
typedef __bf16 bf16x8 __attribute__((ext_vector_type(8)));

DEVINL void gld_lds16(const void* g, void* l) {
  __builtin_amdgcn_global_load_lds(
      (const __attribute__((address_space(1))) unsigned int*)g,
      (__attribute__((address_space(3))) unsigned int*)l, 16, 0, 0);
}

DEVINL unsigned short f2bf(float f) {
  __bf16 h = (__bf16)f;
  return __builtin_bit_cast(unsigned short, h);
}

DEVINL f32x4 mfma16(bf16x8 a, bf16x8 b, f32x4 c) {
  return __builtin_amdgcn_mfma_f32_16x16x32_bf16(a, b, c, 0, 0, 0);
}

// XCD-aware bijective block remap (nwg divisible by 8).
DEVINL void swz3(int& bn, int& bm, int& z) {
  int gx = gridDim.x, gy = gridDim.y;
  int nwg = gx * gy * gridDim.z;
  int flat = blockIdx.x + gx * (blockIdx.y + gy * blockIdx.z);
  int wg = (flat & 7) * (nwg >> 3) + (flat >> 3);
  bn = wg % gx;
  int t = wg / gx;
  bm = t % gy;
  z = t / gy;
}

// ---------------------------------------------------------------------------
// fp32 -> bf16 convert, both activations in one launch (grid 8192 x 256)
// ---------------------------------------------------------------------------
__global__ __launch_bounds__(256) void cvt2_kernel(const float* __restrict__ inA,
                                                   unsigned short* __restrict__ outA,
                                                   const float* __restrict__ inB,
                                                   unsigned short* __restrict__ outB) {
  int bx = blockIdx.x;
  const float* in = bx < 4096 ? inA : inB;
  unsigned short* outp = bx < 4096 ? outA : outB;
  int i = (bx & 4095) * 256 + threadIdx.x;
  float4 v = ((const float4*)in)[i];
  ushort4 o;
  o.x = f2bf(v.x); o.y = f2bf(v.y); o.z = f2bf(v.z); o.w = f2bf(v.w);
  ((ushort4*)outp)[i] = o;
}

// ---------------------------------------------------------------------------
// All 5 weight transposes (W[K][N] fp32 -> Wt[N][K] bf16) in one launch.
// ---------------------------------------------------------------------------
struct TransArgs {
  const float* W[5];
  unsigned short* Wt[5];
};

DEVINL void trans_tile(const float* W, unsigned short* Wt, int K, int N,
                       int xt, int yt) {
  __shared__ float t[32][33];
  int n0 = xt * 32, k0 = yt * 32;
  int tx = threadIdx.x & 31, ty = threadIdx.x >> 5;  // ty 0..7
#pragma unroll
  for (int i = 0; i < 4; i++)
    t[ty + i * 8][tx] = W[(size_t)(k0 + ty + i * 8) * N + n0 + tx];
  __syncthreads();
#pragma unroll
  for (int i = 0; i < 4; i++) {
    int n = ty + i * 8;
    Wt[(size_t)(n0 + n) * K + k0 + tx] = f2bf(t[tx][n]);
  }
}

__global__ __launch_bounds__(256) void transpose_all(TransArgs a) {
  int t = blockIdx.x;
  if (t < 1024)       trans_tile(a.W[0], a.Wt[0], 1024, 1024, t % 32, t / 32);
  else if (t < 3072)  { int l = t - 1024; trans_tile(a.W[1], a.Wt[1], 1024, 2048, l % 64, l / 64); }
  else if (t < 4096)  { int l = t - 3072; trans_tile(a.W[2], a.Wt[2], 1024, 1024, l % 32, l / 32); }
  else if (t < 6144)  { int l = t - 4096; trans_tile(a.W[3], a.Wt[3], 1024, 2048, l % 64, l / 64); }
  else                { int l = t - 6144; trans_tile(a.W[4], a.Wt[4], 2048, 1024, l % 32, l / 32); }
}

// ---------------------------------------------------------------------------
// 8-wave GEMM main loop (BM x BN tile, BK=64, 512 threads, waves 2M x 4N).
// T2 XOR swizzle; double-buffered, one barrier per K-step (m97 order).
// ---------------------------------------------------------------------------
template <int BM, int BN, int MREP, int NREP>
DEVINL void g256_main(const unsigned short* A, const unsigned short* Bt, int K,
                      int bm, int bn, unsigned short* Al, unsigned short* Bl,
                      f32x4 (&acc)[MREP][NREP]) {
  const int tid = threadIdx.x;
  const int wave = tid >> 6, lane = tid & 63;
  const int lr = lane & 15;
  const int lk16 = (lane >> 4) * 16;
  const int wm = wave >> 2, wn = wave & 3;
  const int swz = (lr & 7) << 4;
  const int nk = K >> 6;
  const size_t Kb = (size_t)K * 2;

#pragma unroll
  for (int m = 0; m < MREP; m++)
#pragma unroll
    for (int n = 0; n < NREP; n++) acc[m][n] = f32x4{0.f, 0.f, 0.f, 0.f};

  auto stage = [&](int buf, int kt) {
#pragma unroll
    for (int i = 0; i < BM / 64; i++) {
      int chunk = i * 512 + tid;
      int row = chunk >> 3, cb = (chunk & 7) * 16;
      const char* src = (const char*)A + (size_t)(bm * BM + row) * Kb +
                        kt * 128 + (cb ^ ((row & 7) << 4));
      char* dst = (char*)(Al + (size_t)buf * BM * 64) + (i * 512 + wave * 64) * 16;
      gld_lds16(src, dst);
    }
#pragma unroll
    for (int i = 0; i < BN / 64; i++) {
      int chunk = i * 512 + tid;
      int row = chunk >> 3, cb = (chunk & 7) * 16;
      const char* src = (const char*)Bt + (size_t)(bn * BN + row) * Kb +
                        kt * 128 + (cb ^ ((row & 7) << 4));
      char* dst = (char*)(Bl + (size_t)buf * BN * 64) + (i * 512 + wave * 64) * 16;
      gld_lds16(src, dst);
    }
  };

  stage(0, 0);
  for (int kt = 0; kt < nk; ++kt) {
    __syncthreads();
    if (kt + 1 < nk) stage((kt + 1) & 1, kt + 1);
    const char* ab = (const char*)(Al + (size_t)(kt & 1) * BM * 64);
    const char* bb = (const char*)(Bl + (size_t)(kt & 1) * BN * 64);
#pragma unroll
    for (int kk = 0; kk < 2; kk++) {
      bf16x8 af[MREP], bf[NREP];
#pragma unroll
      for (int m = 0; m < MREP; m++) {
        int row = wm * (BM / 2) + m * 16 + lr;
        af[m] = *(const bf16x8*)(ab + row * 128 + ((kk * 64 + lk16) ^ swz));
      }
#pragma unroll
      for (int n = 0; n < NREP; n++) {
        int row = wn * (BN / 4) + n * 16 + lr;
        bf[n] = *(const bf16x8*)(bb + row * 128 + ((kk * 64 + lk16) ^ swz));
      }
#pragma unroll
      for (int m = 0; m < MREP; m++)
#pragma unroll
        for (int n = 0; n < NREP; n++)
          acc[m][n] = mfma16(af[m], bf[n], acc[m][n]);
    }
  }
}

// ---------------------------------------------------------------------------
// Dual Q-projection: 256x128 tile, grid (8,16,2) = 256 blocks.
// ---------------------------------------------------------------------------
__global__ __launch_bounds__(512, 2) void gemm_q2(const unsigned short* __restrict__ A0,
                                                  const unsigned short* __restrict__ B0,
                                                  const float* __restrict__ bias0,
                                                  unsigned short* __restrict__ C0,
                                                  const unsigned short* __restrict__ A1,
                                                  const unsigned short* __restrict__ B1,
                                                  const float* __restrict__ bias1,
                                                  unsigned short* __restrict__ C1) {
  __shared__ unsigned short Al[2 * 256 * 64];  // 64KB
  __shared__ unsigned short Bl[2 * 128 * 64];  // 32KB
  int bn, bm, z;
  swz3(bn, bm, z);
  const unsigned short* A = z ? A1 : A0;
  const unsigned short* Bt = z ? B1 : B0;
  const float* bias = z ? bias1 : bias0;
  unsigned short* C = z ? C1 : C0;
  const int lane = threadIdx.x & 63, wave = threadIdx.x >> 6;
  const int lr = lane & 15, g4 = lane >> 4;
  const int wm = wave >> 2, wn = wave & 3;
  f32x4 acc[8][2];
  g256_main<256, 128, 8, 2>(A, Bt, 1024, bm, bn, Al, Bl, acc);
#pragma unroll
  for (int n = 0; n < 2; n++) {
    int col = bn * 128 + wn * 32 + n * 16 + lr;
    float bv = bias[col];
#pragma unroll
    for (int m = 0; m < 8; m++) {
      int row0 = bm * 256 + wm * 128 + m * 16 + g4 * 4;
#pragma unroll
      for (int r = 0; r < 4; r++)
        C[(size_t)(row0 + r) * 1024 + col] = f2bf(acc[m][n][r] + bv);
    }
  }
}

// ---------------------------------------------------------------------------
// Dual KV projection: 128x128 tile, 8 waves, grid (16,32,2) = 1024 blocks,
// LDS 64KB -> 2 blocks/CU (barrier drains overlap across blocks, m114).
// K half -> Kbuf [4096][1024]; V half -> V^T [bh][64 d][1024 s].
// ---------------------------------------------------------------------------
__global__ __launch_bounds__(512, 4) void gemm_kv2(const unsigned short* __restrict__ A0,
                                                   const unsigned short* __restrict__ B0,
                                                   const float* __restrict__ bias0,
                                                   unsigned short* __restrict__ K0,
                                                   unsigned short* __restrict__ V0,
                                                   const unsigned short* __restrict__ A1,
                                                   const unsigned short* __restrict__ B1,
                                                   const float* __restrict__ bias1,
                                                   unsigned short* __restrict__ K1,
                                                   unsigned short* __restrict__ V1) {
  __shared__ unsigned short Al[2 * 128 * 64];  // 32KB
  __shared__ unsigned short Bl[2 * 128 * 64];  // 32KB
  int bn, bm, z;
  swz3(bn, bm, z);
  const unsigned short* A = z ? A1 : A0;
  const unsigned short* Bt = z ? B1 : B0;
  const float* bias = z ? bias1 : bias0;
  unsigned short* Kbuf = z ? K1 : K0;
  unsigned short* VtG = z ? V1 : V0;
  const int lane = threadIdx.x & 63, wave = threadIdx.x >> 6;
  const int lr = lane & 15, g4 = lane >> 4;
  const int wm = wave >> 2, wn = wave & 3;
  f32x4 acc[4][2];
  g256_main<128, 128, 4, 2>(A, Bt, 1024, bm, bn, Al, Bl, acc);
#pragma unroll
  for (int n = 0; n < 2; n++) {
    int col = bn * 128 + wn * 32 + n * 16 + lr;
    float bv = bias[col];
#pragma unroll
    for (int m = 0; m < 4; m++) {
      int row0 = bm * 128 + wm * 64 + m * 16 + g4 * 4;
      if (col < 1024) {
#pragma unroll
        for (int r = 0; r < 4; r++)
          Kbuf[(size_t)(row0 + r) * 1024 + col] = f2bf(acc[m][n][r] + bv);
      } else {
        int h = (col - 1024) >> 6, d = (col - 1024) & 63;
        int b = row0 >> 10, s = row0 & 1023;
        ushort4 pk;
        pk.x = f2bf(acc[m][n][0] + bv);
        pk.y = f2bf(acc[m][n][1] + bv);
        pk.z = f2bf(acc[m][n][2] + bv);
        pk.w = f2bf(acc[m][n][3] + bv);
        *(ushort4*)&VtG[((size_t)(b * 16 + h) * 64 + d) * 1024 + s] = pk;
      }
    }
  }
}

// ---------------------------------------------------------------------------
// Output projection: fused[4096][2048] @ Wt_p^T + bp -> fp32 out [4096][1024].
// 128x128 tile -> grid MUST be (8,32) (N/128=8, M/128=32).
// ---------------------------------------------------------------------------
__global__ __launch_bounds__(512, 4) void gemm_out(const unsigned short* __restrict__ A,
                                                   const unsigned short* __restrict__ Bt,
                                                   const float* __restrict__ bias,
                                                   float* __restrict__ C) {
  __shared__ unsigned short Al[2 * 128 * 64];  // 32KB
  __shared__ unsigned short Bl[2 * 128 * 64];  // 32KB
  int bn, bm, z;
  swz3(bn, bm, z);
  const int lane = threadIdx.x & 63, wave = threadIdx.x >> 6;
  const int lr = lane & 15, g4 = lane >> 4;
  const int wm = wave >> 2, wn = wave & 3;
  f32x4 acc[4][2];
  g256_main<128, 128, 4, 2>(A, Bt, 2048, bm, bn, Al, Bl, acc);
#pragma unroll
  for (int n = 0; n < 2; n++) {
    int col = bn * 128 + wn * 32 + n * 16 + lr;
    float bv = bias[col];
#pragma unroll
    for (int m = 0; m < 4; m++) {
      int row0 = bm * 128 + wm * 64 + m * 16 + g4 * 4;
#pragma unroll
      for (int r = 0; r < 4; r++)
        C[(size_t)(row0 + r) * 1024 + col] = acc[m][n][r] + bv;
    }
  }
  (void)z;
}

// ---------------------------------------------------------------------------
// Fused dual-direction flash attention, QBLK=128, KVBLK=128, in-register
// softmax (R13 body, HW-verified). One launch: grid (16,64), LDS 64KB ->
// 2 blocks/CU. qt=y&7, u=x+(y>>3)*16, dir=u>>6, bh=u&63.
// ---------------------------------------------------------------------------
__global__ __launch_bounds__(256, 2) void attn_fused(const unsigned short* __restrict__ Qs,
                                                     const unsigned short* __restrict__ Ks,
                                                     const unsigned short* __restrict__ Vs,
                                                     const unsigned short* __restrict__ Qf,
                                                     const unsigned short* __restrict__ Kf,
                                                     const unsigned short* __restrict__ Vf,
                                                     unsigned short* __restrict__ Out) {
  __shared__ unsigned short Kl[2][128 * 64];  // 32KB dbuf K tile [key][d]
  __shared__ unsigned short Vt[2][64 * 128];  // 32KB dbuf V^T tile [d][key]

  const int tid = threadIdx.x;
  const int wave = tid >> 6, lane = tid & 63;
  const int qt = blockIdx.y & 7;
  const int u = blockIdx.x + (blockIdx.y >> 3) * 16;
  const int dir = u >> 6, bh = u & 63;
  const int b = bh >> 4, h = bh & 15;
  const unsigned short* Q = dir ? Qf : Qs;
  const unsigned short* Kg = dir ? Kf : Ks;
  const unsigned short* VtG = dir ? Vf : Vs;
  const int outColBase = dir ? 1024 : 0;
  const float clo = dir ? -3.0e38f : -100.f;
  const float chi = dir ? 3.0e38f : 100.f;

  const int q16 = lane & 15;       // this lane's q-row (softmax) & output col
  const int g4 = lane >> 4;        // key-quarter group
  const int lk16 = g4 * 16;

  // Q fragments (B-operand): lane holds Q[q16][d-chunk g4*8..]
  bf16x8 qa[2][2];
#pragma unroll
  for (int g = 0; g < 2; g++) {
    const size_t qrow = (size_t)b * 1024 + qt * 128 + wave * 32 + g * 16 + q16;
    const char* qp = (const char*)(Q + qrow * 1024 + h * 64);
    qa[g][0] = *(const bf16x8*)(qp + lk16);
    qa[g][1] = *(const bf16x8*)(qp + 64 + lk16);
  }

  f32x4 acc[2][4] = {};
  float mrun[2] = {-1e30f, -1e30f}, lsum[2] = {0.f, 0.f};

  const char* kbase = (const char*)Kg + (size_t)b * 1024 * 2048 + h * 128;
  const char* vbase = (const char*)VtG + (size_t)bh * 64 * 2048;

  auto stage = [&](int buf, int kt) {
#pragma unroll
    for (int p2 = 0; p2 < 4; p2++) {
      int chunk = tid + p2 * 256;                  // 0..1023
      int r = chunk >> 3, cb = (chunk & 7) * 16;   // key row, 16B col
      const char* src = kbase + (size_t)(kt * 128 + r) * 2048 + (cb ^ ((r & 7) << 4));
      char* dst = (char*)&Kl[buf][0] + (p2 * 256 + wave * 64) * 16;  // wave-uniform
      gld_lds16(src, dst);
    }
#pragma unroll
    for (int p2 = 0; p2 < 4; p2++) {
      int chunk = tid + p2 * 256;
      int d = chunk >> 4, ko = (chunk & 15) * 16;
      const char* src = vbase + (size_t)d * 2048 + kt * 256 + (ko ^ ((d & 7) << 4));
      char* dst = (char*)&Vt[buf][0] + (p2 * 256 + wave * 64) * 16;  // wave-uniform
      gld_lds16(src, dst);
    }
  };

  stage(0, 0);
  for (int kt = 0; kt < 8; ++kt) {
    __syncthreads();                 // stage(kt) complete; prev reads done
    if (kt < 7) stage((kt + 1) & 1, kt + 1);  // flies during compute(kt)
    const char* kb = (const char*)&Kl[kt & 1][0];
    const char* vb = (const char*)&Vt[kt & 1][0];

#pragma unroll
    for (int g = 0; g < 2; g++) {
      // swapped QK^T: st[t8][r] = S[key = t8*16 + 4*g4 + r][q16]
      f32x4 st[8];
#pragma unroll
      for (int t8 = 0; t8 < 8; t8++) {
        int krow = t8 * 16 + q16;
        int sw = (krow & 7) << 4;
        const char* kr = kb + krow * 128;
        bf16x8 kb0 = *(const bf16x8*)(kr + ((0 + lk16) ^ sw));
        bf16x8 kb1 = *(const bf16x8*)(kr + ((64 + lk16) ^ sw));
        f32x4 s = {};
        s = mfma16(kb0, qa[g][0], s);   // K as A, Q as B -> D[key][q]
        s = mfma16(kb1, qa[g][1], s);
#pragma unroll
        for (int r = 0; r < 4; r++)
          s[r] = fminf(fmaxf(s[r] * 0.125f, clo), chi);
        st[t8] = s;
      }

      // row-softmax for q=q16: local tree + 2 shfl
      float tmax[8];
#pragma unroll
      for (int t8 = 0; t8 < 8; t8++)
        tmax[t8] = fmaxf(fmaxf(st[t8][0], st[t8][1]), fmaxf(st[t8][2], st[t8][3]));
      float mx = fmaxf(fmaxf(fmaxf(tmax[0], tmax[1]), fmaxf(tmax[2], tmax[3])),
                       fmaxf(fmaxf(tmax[4], tmax[5]), fmaxf(tmax[6], tmax[7])));
      mx = fmaxf(mx, __shfl_xor(mx, 16, 64));
      mx = fmaxf(mx, __shfl_xor(mx, 32, 64));
      float mnew = fmaxf(mrun[g], mx);
      float al = __expf(mrun[g] - mnew);
      mrun[g] = mnew;
      float sum = 0.f;
#pragma unroll
      for (int t8 = 0; t8 < 8; t8++) {
#pragma unroll
        for (int r = 0; r < 4; r++) {
          float pv = __expf(st[t8][r] - mnew);
          st[t8][r] = pv;
          sum += pv;
        }
      }
      sum += __shfl_xor(sum, 16, 64);
      sum += __shfl_xor(sum, 32, 64);
      lsum[g] = lsum[g] * al + sum;

      // rescale acc rows (acc row q = 4*g4+r; al lives in lanes with l&15==q)
      float alr[4];
#pragma unroll
      for (int r = 0; r < 4; r++) alr[r] = __shfl(al, 4 * g4 + r, 64);
#pragma unroll
      for (int n = 0; n < 4; n++)
#pragma unroll
        for (int r = 0; r < 4; r++) acc[g][n][r] *= alr[r];

      // pack P to bf16 pairs
      unsigned int plo[8], phi[8];
#pragma unroll
      for (int t8 = 0; t8 < 8; t8++) {
        plo[t8] = ((unsigned)f2bf(st[t8][1]) << 16) | f2bf(st[t8][0]);
        phi[t8] = ((unsigned)f2bf(st[t8][3]) << 16) | f2bf(st[t8][2]);
      }

      // redistribute (HW-verified lane algebra)
      const int s0 = q16 + ((g4 & 1) << 5);
      const int s1 = s0 + 16;
      const bool odd = (g4 & 2) != 0;
      bf16x8 pa[4];
#pragma unroll
      for (int kc = 0; kc < 4; kc++) {
        unsigned ae = __shfl(plo[2 * kc], s0, 64), be = __shfl(phi[2 * kc], s0, 64);
        unsigned ao = __shfl(plo[2 * kc + 1], s0, 64), bo = __shfl(phi[2 * kc + 1], s0, 64);
        unsigned ce = __shfl(plo[2 * kc], s1, 64), de = __shfl(phi[2 * kc], s1, 64);
        unsigned co = __shfl(plo[2 * kc + 1], s1, 64), dd = __shfl(phi[2 * kc + 1], s1, 64);
        uint4 w;
        w.x = odd ? ao : ae;
        w.y = odd ? bo : be;
        w.z = odd ? co : ce;
        w.w = odd ? dd : de;
        pa[kc] = __builtin_bit_cast(bf16x8, w);
      }

      // PV: O += P[16x128] @ V[128x64] (V from LDS)
#pragma unroll
      for (int n = 0; n < 4; n++) {
        int vr = n * 16 + q16;
        int sw = (vr & 7) << 4;
        const char* vp = vb + vr * 256;
#pragma unroll
        for (int kc = 0; kc < 4; kc++) {
          bf16x8 vbv = *(const bf16x8*)(vp + ((kc * 64 + lk16) ^ sw));
          acc[g][n] = mfma16(pa[kc], vbv, acc[g][n]);
        }
      }
    }
  }

  // epilogue: O / l -> bf16 fused
#pragma unroll
  for (int g = 0; g < 2; g++) {
    float lr4[4];
#pragma unroll
    for (int r = 0; r < 4; r++) lr4[r] = __shfl(lsum[g], 4 * g4 + r, 64);
    const size_t orow0 = (size_t)b * 1024 + qt * 128 + wave * 32 + g * 16 + g4 * 4;
#pragma unroll
    for (int n = 0; n < 4; n++) {
      int col = outColBase + h * 64 + n * 16 + q16;
#pragma unroll
      for (int r = 0; r < 4; r++) {
        float o = acc[g][n][r] / lr4[r];
        Out[(orow0 + r) * 2048 + col] = f2bf(o);
      }
    }
  }
}

// ---------------------------------------------------------------------------
// In-place LayerNorm over rows of 1024 fp32 (1 block = 1 row, 256 thr)
// ---------------------------------------------------------------------------
__global__ __launch_bounds__(256) void ln_inplace(float* __restrict__ io,
                                                  const float* __restrict__ gamma,
                                                  const float* __restrict__ beta) {
  __shared__ float red[8];
  int row = blockIdx.x, tid = threadIdx.x;
  float* p = io + (size_t)row * 1024;
  float4 x = ((const float4*)p)[tid];
  float s = x.x + x.y + x.z + x.w;
  float s2 = x.x * x.x + x.y * x.y + x.z * x.z + x.w * x.w;
#pragma unroll
  for (int off = 32; off; off >>= 1) {
    s += __shfl_down(s, off, 64);
    s2 += __shfl_down(s2, off, 64);
  }
  int wv = tid >> 6;
  if ((tid & 63) == 0) { red[wv] = s; red[4 + wv] = s2; }
  __syncthreads();
  if (tid == 0) {
    red[0] = red[0] + red[1] + red[2] + red[3];
    red[4] = red[4] + red[5] + red[6] + red[7];
  }
  __syncthreads();
  float mu = red[0] * (1.f / 1024.f);
  float var = red[4] * (1.f / 1024.f) - mu * mu;
  float inv = rsqrtf(var + 1e-5f);
  float4 g = ((const float4*)gamma)[tid];
  float4 bb = ((const float4*)beta)[tid];
  x.x = (x.x - mu) * inv * g.x + bb.x;
  x.y = (x.y - mu) * inv * g.y + bb.y;
  x.z = (x.z - mu) * inv * g.z + bb.z;
  x.w = (x.w - mu) * inv * g.w + bb.w;
  ((float4*)p)[tid] = x;
}

// ---------------------------------------------------------------------------
extern "C" void kernel_launch(void* const* d_in, const int* in_sizes, int n_in,
                              void* d_out, int out_size, void* d_ws, size_t ws_size,
                              hipStream_t stream) {
  (void)in_sizes; (void)n_in; (void)out_size; (void)ws_size;
  const float* image = (const float*)d_in[0];
  const float* wavef = (const float*)d_in[1];
  const float* Wq_i  = (const float*)d_in[2];
  const float* bq_i  = (const float*)d_in[3];
  const float* Wkv_w = (const float*)d_in[4];
  const float* bkv_w = (const float*)d_in[5];
  const float* Wq_w  = (const float*)d_in[6];
  const float* bq_w  = (const float*)d_in[7];
  const float* Wkv_i = (const float*)d_in[8];
  const float* bkv_i = (const float*)d_in[9];
  const float* Wp    = (const float*)d_in[10];
  const float* bp    = (const float*)d_in[11];
  const float* gamma = (const float*)d_in[12];
  const float* beta  = (const float*)d_in[13];
  float* out = (float*)d_out;

  char* ws = (char*)d_ws;
  unsigned short* Xi = (unsigned short*)ws;                       // 8 MiB
  unsigned short* Xw = (unsigned short*)ws + 4096ull * 1024;      // 8 MiB
  unsigned short* fused = (unsigned short*)ws;                    // 16 MiB alias
  size_t off = 16ull << 20;
  auto take = [&](size_t bytes) { void* p = ws + off; off += bytes; return p; };
  unsigned short* Wt_qi  = (unsigned short*)take(2ull << 20);
  unsigned short* Wt_kvw = (unsigned short*)take(4ull << 20);
  unsigned short* Wt_qw  = (unsigned short*)take(2ull << 20);
  unsigned short* Wt_kvi = (unsigned short*)take(4ull << 20);
  unsigned short* Wt_p   = (unsigned short*)take(4ull << 20);
  unsigned short* q_s    = (unsigned short*)take(8ull << 20);
  unsigned short* q_f    = (unsigned short*)take(8ull << 20);
  unsigned short* kvK_w  = (unsigned short*)take(8ull << 20);
  unsigned short* VtG_w  = (unsigned short*)take(8ull << 20);
  unsigned short* kvK_s  = (unsigned short*)take(8ull << 20);
  unsigned short* VtG_s  = (unsigned short*)take(8ull << 20);

  // 1) convert both activations to bf16
  cvt2_kernel<<<8192, 256, 0, stream>>>(image, Xi, wavef, Xw);
  // 2) all 5 weight transposes
  TransArgs ta;
  ta.W[0] = Wq_i;  ta.Wt[0] = Wt_qi;
  ta.W[1] = Wkv_w; ta.Wt[1] = Wt_kvw;
  ta.W[2] = Wq_w;  ta.Wt[2] = Wt_qw;
  ta.W[3] = Wkv_i; ta.Wt[3] = Wt_kvi;
  ta.W[4] = Wp;    ta.Wt[4] = Wt_p;
  transpose_all<<<8192, 256, 0, stream>>>(ta);
  // 3) projections
  gemm_q2<<<dim3(8, 16, 2), 512, 0, stream>>>(Xi, Wt_qi, bq_i, q_s,
                                              Xw, Wt_qw, bq_w, q_f);
  gemm_kv2<<<dim3(16, 32, 2), 512, 0, stream>>>(Xw, Wt_kvw, bkv_w, kvK_w, VtG_w,
                                                Xi, Wt_kvi, bkv_i, kvK_s, VtG_s);
  // 4) fused dual-direction cross attention (one launch)
  attn_fused<<<dim3(16, 64), 256, 0, stream>>>(q_s, kvK_w, VtG_w,
                                               q_f, kvK_s, VtG_s, fused);
  // 5) output projection (grid (8,32): N=1024 -> 8 col-tiles) + 6) LayerNorm
  gemm_out<<<dim3(8, 32), 512, 0, stream>>>(fused, Wt_p, bp, out);
  ln_inplace<<<4096, 256, 0, stream>>>(out, gamma, beta);
}

// Round 17
// 209.307 us; speedup vs baseline: 1.2869x; 1.0288x over previous
//
#include <hip/hip_runtime.h>
#include <hip/hip_bf16.h>

#define DEVINL __device__ __forceinline__

typedef float f32x4 __attribute__((ext_vector_type(4)));
typedef __bf16 bf16x8 __attribute__((ext_vector_type(8)));

DEVINL void gld_lds16(const void* g, void* l) {
  __builtin_amdgcn_global_load_lds(
      (const __attribute__((address_space(1))) unsigned int*)g,
      (__attribute__((address_space(3))) unsigned int*)l, 16, 0, 0);
}

DEVINL unsigned short f2bf(float f) {
  __bf16 h = (__bf16)f;
  return __builtin_bit_cast(unsigned short, h);
}

DEVINL f32x4 mfma16(bf16x8 a, bf16x8 b, f32x4 c) {
  return __builtin_amdgcn_mfma_f32_16x16x32_bf16(a, b, c, 0, 0, 0);
}

// XCD-aware bijective block remap (nwg divisible by 8).
DEVINL void swz3(int& bn, int& bm, int& z) {
  int gx = gridDim.x, gy = gridDim.y;
  int nwg = gx * gy * gridDim.z;
  int flat = blockIdx.x + gx * (blockIdx.y + gy * blockIdx.z);
  int wg = (flat & 7) * (nwg >> 3) + (flat >> 3);
  bn = wg % gx;
  int t = wg / gx;
  bm = t % gy;
  z = t / gy;
}

// ---------------------------------------------------------------------------
// fp32 -> bf16 convert, both activations in one launch (grid 8192 x 256)
// ---------------------------------------------------------------------------
__global__ __launch_bounds__(256) void cvt2_kernel(const float* __restrict__ inA,
                                                   unsigned short* __restrict__ outA,
                                                   const float* __restrict__ inB,
                                                   unsigned short* __restrict__ outB) {
  int bx = blockIdx.x;
  const float* in = bx < 4096 ? inA : inB;
  unsigned short* outp = bx < 4096 ? outA : outB;
  int i = (bx & 4095) * 256 + threadIdx.x;
  float4 v = ((const float4*)in)[i];
  ushort4 o;
  o.x = f2bf(v.x); o.y = f2bf(v.y); o.z = f2bf(v.z); o.w = f2bf(v.w);
  ((ushort4*)outp)[i] = o;
}

// ---------------------------------------------------------------------------
// All 5 weight transposes (W[K][N] fp32 -> Wt[N][K] bf16) in one launch.
// ---------------------------------------------------------------------------
struct TransArgs {
  const float* W[5];
  unsigned short* Wt[5];
};

DEVINL void trans_tile(const float* W, unsigned short* Wt, int K, int N,
                       int xt, int yt) {
  __shared__ float t[32][33];
  int n0 = xt * 32, k0 = yt * 32;
  int tx = threadIdx.x & 31, ty = threadIdx.x >> 5;  // ty 0..7
#pragma unroll
  for (int i = 0; i < 4; i++)
    t[ty + i * 8][tx] = W[(size_t)(k0 + ty + i * 8) * N + n0 + tx];
  __syncthreads();
#pragma unroll
  for (int i = 0; i < 4; i++) {
    int n = ty + i * 8;
    Wt[(size_t)(n0 + n) * K + k0 + tx] = f2bf(t[tx][n]);
  }
}

__global__ __launch_bounds__(256) void transpose_all(TransArgs a) {
  int t = blockIdx.x;
  if (t < 1024)       trans_tile(a.W[0], a.Wt[0], 1024, 1024, t % 32, t / 32);
  else if (t < 3072)  { int l = t - 1024; trans_tile(a.W[1], a.Wt[1], 1024, 2048, l % 64, l / 64); }
  else if (t < 4096)  { int l = t - 3072; trans_tile(a.W[2], a.Wt[2], 1024, 1024, l % 32, l / 32); }
  else if (t < 6144)  { int l = t - 4096; trans_tile(a.W[3], a.Wt[3], 1024, 2048, l % 64, l / 64); }
  else                { int l = t - 6144; trans_tile(a.W[4], a.Wt[4], 2048, 1024, l % 32, l / 32); }
}

// ---------------------------------------------------------------------------
// 8-wave GEMM main loop (BM x BN tile, BK=64, 512 threads, waves 2M x 4N).
// T2 XOR swizzle; double-buffered, one barrier per K-step (m97 order).
// ---------------------------------------------------------------------------
template <int BM, int BN, int MREP, int NREP>
DEVINL void g256_main(const unsigned short* A, const unsigned short* Bt, int K,
                      int bm, int bn, unsigned short* Al, unsigned short* Bl,
                      f32x4 (&acc)[MREP][NREP]) {
  const int tid = threadIdx.x;
  const int wave = tid >> 6, lane = tid & 63;
  const int lr = lane & 15;
  const int lk16 = (lane >> 4) * 16;
  const int wm = wave >> 2, wn = wave & 3;
  const int swz = (lr & 7) << 4;
  const int nk = K >> 6;
  const size_t Kb = (size_t)K * 2;

#pragma unroll
  for (int m = 0; m < MREP; m++)
#pragma unroll
    for (int n = 0; n < NREP; n++) acc[m][n] = f32x4{0.f, 0.f, 0.f, 0.f};

  auto stage = [&](int buf, int kt) {
#pragma unroll
    for (int i = 0; i < BM / 64; i++) {
      int chunk = i * 512 + tid;
      int row = chunk >> 3, cb = (chunk & 7) * 16;
      const char* src = (const char*)A + (size_t)(bm * BM + row) * Kb +
                        kt * 128 + (cb ^ ((row & 7) << 4));
      char* dst = (char*)(Al + (size_t)buf * BM * 64) + (i * 512 + wave * 64) * 16;
      gld_lds16(src, dst);
    }
#pragma unroll
    for (int i = 0; i < BN / 64; i++) {
      int chunk = i * 512 + tid;
      int row = chunk >> 3, cb = (chunk & 7) * 16;
      const char* src = (const char*)Bt + (size_t)(bn * BN + row) * Kb +
                        kt * 128 + (cb ^ ((row & 7) << 4));
      char* dst = (char*)(Bl + (size_t)buf * BN * 64) + (i * 512 + wave * 64) * 16;
      gld_lds16(src, dst);
    }
  };

  stage(0, 0);
  for (int kt = 0; kt < nk; ++kt) {
    __syncthreads();
    if (kt + 1 < nk) stage((kt + 1) & 1, kt + 1);
    const char* ab = (const char*)(Al + (size_t)(kt & 1) * BM * 64);
    const char* bb = (const char*)(Bl + (size_t)(kt & 1) * BN * 64);
#pragma unroll
    for (int kk = 0; kk < 2; kk++) {
      bf16x8 af[MREP], bf[NREP];
#pragma unroll
      for (int m = 0; m < MREP; m++) {
        int row = wm * (BM / 2) + m * 16 + lr;
        af[m] = *(const bf16x8*)(ab + row * 128 + ((kk * 64 + lk16) ^ swz));
      }
#pragma unroll
      for (int n = 0; n < NREP; n++) {
        int row = wn * (BN / 4) + n * 16 + lr;
        bf[n] = *(const bf16x8*)(bb + row * 128 + ((kk * 64 + lk16) ^ swz));
      }
#pragma unroll
      for (int m = 0; m < MREP; m++)
#pragma unroll
        for (int n = 0; n < NREP; n++)
          acc[m][n] = mfma16(af[m], bf[n], acc[m][n]);
    }
  }
}

// ---------------------------------------------------------------------------
// Dual Q-projection: 256x128 tile, grid (8,16,2) = 256 blocks.
// ---------------------------------------------------------------------------
__global__ __launch_bounds__(512, 2) void gemm_q2(const unsigned short* __restrict__ A0,
                                                  const unsigned short* __restrict__ B0,
                                                  const float* __restrict__ bias0,
                                                  unsigned short* __restrict__ C0,
                                                  const unsigned short* __restrict__ A1,
                                                  const unsigned short* __restrict__ B1,
                                                  const float* __restrict__ bias1,
                                                  unsigned short* __restrict__ C1) {
  __shared__ unsigned short Al[2 * 256 * 64];  // 64KB
  __shared__ unsigned short Bl[2 * 128 * 64];  // 32KB
  int bn, bm, z;
  swz3(bn, bm, z);
  const unsigned short* A = z ? A1 : A0;
  const unsigned short* Bt = z ? B1 : B0;
  const float* bias = z ? bias1 : bias0;
  unsigned short* C = z ? C1 : C0;
  const int lane = threadIdx.x & 63, wave = threadIdx.x >> 6;
  const int lr = lane & 15, g4 = lane >> 4;
  const int wm = wave >> 2, wn = wave & 3;
  f32x4 acc[8][2];
  g256_main<256, 128, 8, 2>(A, Bt, 1024, bm, bn, Al, Bl, acc);
#pragma unroll
  for (int n = 0; n < 2; n++) {
    int col = bn * 128 + wn * 32 + n * 16 + lr;
    float bv = bias[col];
#pragma unroll
    for (int m = 0; m < 8; m++) {
      int row0 = bm * 256 + wm * 128 + m * 16 + g4 * 4;
#pragma unroll
      for (int r = 0; r < 4; r++)
        C[(size_t)(row0 + r) * 1024 + col] = f2bf(acc[m][n][r] + bv);
    }
  }
}

// ---------------------------------------------------------------------------
// Dual KV projection: 128x128 tile, 8 waves, grid (16,32,2) = 1024 blocks,
// LDS 64KB -> 2 blocks/CU. K half -> Kbuf; V half -> V^T [bh][64 d][1024 s].
// ---------------------------------------------------------------------------
__global__ __launch_bounds__(512, 4) void gemm_kv2(const unsigned short* __restrict__ A0,
                                                   const unsigned short* __restrict__ B0,
                                                   const float* __restrict__ bias0,
                                                   unsigned short* __restrict__ K0,
                                                   unsigned short* __restrict__ V0,
                                                   const unsigned short* __restrict__ A1,
                                                   const unsigned short* __restrict__ B1,
                                                   const float* __restrict__ bias1,
                                                   unsigned short* __restrict__ K1,
                                                   unsigned short* __restrict__ V1) {
  __shared__ unsigned short Al[2 * 128 * 64];  // 32KB
  __shared__ unsigned short Bl[2 * 128 * 64];  // 32KB
  int bn, bm, z;
  swz3(bn, bm, z);
  const unsigned short* A = z ? A1 : A0;
  const unsigned short* Bt = z ? B1 : B0;
  const float* bias = z ? bias1 : bias0;
  unsigned short* Kbuf = z ? K1 : K0;
  unsigned short* VtG = z ? V1 : V0;
  const int lane = threadIdx.x & 63, wave = threadIdx.x >> 6;
  const int lr = lane & 15, g4 = lane >> 4;
  const int wm = wave >> 2, wn = wave & 3;
  f32x4 acc[4][2];
  g256_main<128, 128, 4, 2>(A, Bt, 1024, bm, bn, Al, Bl, acc);
#pragma unroll
  for (int n = 0; n < 2; n++) {
    int col = bn * 128 + wn * 32 + n * 16 + lr;
    float bv = bias[col];
#pragma unroll
    for (int m = 0; m < 4; m++) {
      int row0 = bm * 128 + wm * 64 + m * 16 + g4 * 4;
      if (col < 1024) {
#pragma unroll
        for (int r = 0; r < 4; r++)
          Kbuf[(size_t)(row0 + r) * 1024 + col] = f2bf(acc[m][n][r] + bv);
      } else {
        int h = (col - 1024) >> 6, d = (col - 1024) & 63;
        int b = row0 >> 10, s = row0 & 1023;
        ushort4 pk;
        pk.x = f2bf(acc[m][n][0] + bv);
        pk.y = f2bf(acc[m][n][1] + bv);
        pk.z = f2bf(acc[m][n][2] + bv);
        pk.w = f2bf(acc[m][n][3] + bv);
        *(ushort4*)&VtG[((size_t)(b * 16 + h) * 64 + d) * 1024 + s] = pk;
      }
    }
  }
}

// ---------------------------------------------------------------------------
// Output projection: fused[4096][2048] @ Wt_p^T + bp -> fp32 out [4096][1024].
// 128x128 tile -> grid (8,32).
// ---------------------------------------------------------------------------
__global__ __launch_bounds__(512, 4) void gemm_out(const unsigned short* __restrict__ A,
                                                   const unsigned short* __restrict__ Bt,
                                                   const float* __restrict__ bias,
                                                   float* __restrict__ C) {
  __shared__ unsigned short Al[2 * 128 * 64];  // 32KB
  __shared__ unsigned short Bl[2 * 128 * 64];  // 32KB
  int bn, bm, z;
  swz3(bn, bm, z);
  const int lane = threadIdx.x & 63, wave = threadIdx.x >> 6;
  const int lr = lane & 15, g4 = lane >> 4;
  const int wm = wave >> 2, wn = wave & 3;
  f32x4 acc[4][2];
  g256_main<128, 128, 4, 2>(A, Bt, 2048, bm, bn, Al, Bl, acc);
#pragma unroll
  for (int n = 0; n < 2; n++) {
    int col = bn * 128 + wn * 32 + n * 16 + lr;
    float bv = bias[col];
#pragma unroll
    for (int m = 0; m < 4; m++) {
      int row0 = bm * 128 + wm * 64 + m * 16 + g4 * 4;
#pragma unroll
      for (int r = 0; r < 4; r++)
        C[(size_t)(row0 + r) * 1024 + col] = acc[m][n][r] + bv;
    }
  }
  (void)z;
}

// ---------------------------------------------------------------------------
// Fused dual-direction flash attention, QBLK=128, KVBLK=128, in-register
// swapped-QK softmax + defer-max (T13). P transport via wave-local per-wave
// LDS (8 ds_write_b64 + 4 ds_read_b128, no barrier, R10 layout) instead of
// 32 ds_bpermute. LDS 80KB -> 2 blocks/CU. Grid (16,64).
// ---------------------------------------------------------------------------
__global__ __launch_bounds__(256, 2) void attn_fused(const unsigned short* __restrict__ Qs,
                                                     const unsigned short* __restrict__ Ks,
                                                     const unsigned short* __restrict__ Vs,
                                                     const unsigned short* __restrict__ Qf,
                                                     const unsigned short* __restrict__ Kf,
                                                     const unsigned short* __restrict__ Vf,
                                                     unsigned short* __restrict__ Out) {
  __shared__ unsigned short Kl[2][128 * 64];  // 32KB dbuf K tile [key][d]
  __shared__ unsigned short Vt[2][64 * 128];  // 32KB dbuf V^T tile [d][key]
  __shared__ unsigned short Pl[4][16 * 128];  // 16KB per-wave P (wave-local)

  const int tid = threadIdx.x;
  const int wave = tid >> 6, lane = tid & 63;
  const int qt = blockIdx.y & 7;
  const int u = blockIdx.x + (blockIdx.y >> 3) * 16;
  const int dir = u >> 6, bh = u & 63;
  const int b = bh >> 4, h = bh & 15;
  const unsigned short* Q = dir ? Qf : Qs;
  const unsigned short* Kg = dir ? Kf : Ks;
  const unsigned short* VtG = dir ? Vf : Vs;
  const int outColBase = dir ? 1024 : 0;
  const float clo = dir ? -3.0e38f : -100.f;
  const float chi = dir ? 3.0e38f : 100.f;

  const int q16 = lane & 15;       // this lane's q-row (softmax) & output col
  const int g4 = lane >> 4;        // key-quarter group
  const int lk16 = g4 * 16;

  // Q fragments (B-operand): lane holds Q[q16][d-chunk g4*8..]
  bf16x8 qa[2][2];
#pragma unroll
  for (int g = 0; g < 2; g++) {
    const size_t qrow = (size_t)b * 1024 + qt * 128 + wave * 32 + g * 16 + q16;
    const char* qp = (const char*)(Q + qrow * 1024 + h * 64);
    qa[g][0] = *(const bf16x8*)(qp + lk16);
    qa[g][1] = *(const bf16x8*)(qp + 64 + lk16);
  }

  f32x4 acc[2][4] = {};
  float mrun[2] = {-1e30f, -1e30f}, lsum[2] = {0.f, 0.f};

  const char* kbase = (const char*)Kg + (size_t)b * 1024 * 2048 + h * 128;
  const char* vbase = (const char*)VtG + (size_t)bh * 64 * 2048;

  auto stage = [&](int buf, int kt) {
#pragma unroll
    for (int p2 = 0; p2 < 4; p2++) {
      int chunk = tid + p2 * 256;                  // 0..1023
      int r = chunk >> 3, cb = (chunk & 7) * 16;   // key row, 16B col
      const char* src = kbase + (size_t)(kt * 128 + r) * 2048 + (cb ^ ((r & 7) << 4));
      char* dst = (char*)&Kl[buf][0] + (p2 * 256 + wave * 64) * 16;  // wave-uniform
      gld_lds16(src, dst);
    }
#pragma unroll
    for (int p2 = 0; p2 < 4; p2++) {
      int chunk = tid + p2 * 256;
      int d = chunk >> 4, ko = (chunk & 15) * 16;
      const char* src = vbase + (size_t)d * 2048 + kt * 256 + (ko ^ ((d & 7) << 4));
      char* dst = (char*)&Vt[buf][0] + (p2 * 256 + wave * 64) * 16;  // wave-uniform
      gld_lds16(src, dst);
    }
  };

  char* pb = (char*)&Pl[wave][0];

  stage(0, 0);
  for (int kt = 0; kt < 8; ++kt) {
    __syncthreads();                 // stage(kt) complete; prev reads done
    if (kt < 7) stage((kt + 1) & 1, kt + 1);  // flies during compute(kt)
    const char* kb = (const char*)&Kl[kt & 1][0];
    const char* vb = (const char*)&Vt[kt & 1][0];

#pragma unroll
    for (int g = 0; g < 2; g++) {
      // swapped QK^T: st[t8][r] = S[key = t8*16 + 4*g4 + r][q16]
      f32x4 st[8];
#pragma unroll
      for (int t8 = 0; t8 < 8; t8++) {
        int krow = t8 * 16 + q16;
        int sw = (krow & 7) << 4;
        const char* kr = kb + krow * 128;
        bf16x8 kb0 = *(const bf16x8*)(kr + ((0 + lk16) ^ sw));
        bf16x8 kb1 = *(const bf16x8*)(kr + ((64 + lk16) ^ sw));
        f32x4 s = {};
        s = mfma16(kb0, qa[g][0], s);   // K as A, Q as B -> D[key][q]
        s = mfma16(kb1, qa[g][1], s);
#pragma unroll
        for (int r = 0; r < 4; r++)
          s[r] = fminf(fmaxf(s[r] * 0.125f, clo), chi);
        st[t8] = s;
      }

      // row-max for q=q16: local tree + 2 shfl
      float tmax[8];
#pragma unroll
      for (int t8 = 0; t8 < 8; t8++)
        tmax[t8] = fmaxf(fmaxf(st[t8][0], st[t8][1]), fmaxf(st[t8][2], st[t8][3]));
      float mx = fmaxf(fmaxf(fmaxf(tmax[0], tmax[1]), fmaxf(tmax[2], tmax[3])),
                       fmaxf(fmaxf(tmax[4], tmax[5]), fmaxf(tmax[6], tmax[7])));
      mx = fmaxf(mx, __shfl_xor(mx, 16, 64));
      mx = fmaxf(mx, __shfl_xor(mx, 32, 64));

      // defer-max (T13, THR=8): rescale only if some row's max grew > THR
      if (!__all(mx <= mrun[g] + 8.f)) {
        float mnew = fmaxf(mrun[g], mx);
        float al = __expf(mrun[g] - mnew);
        mrun[g] = mnew;
        lsum[g] *= al;
        float alr[4];
#pragma unroll
        for (int r = 0; r < 4; r++) alr[r] = __shfl(al, 4 * g4 + r, 64);
#pragma unroll
        for (int n = 0; n < 4; n++)
#pragma unroll
          for (int r = 0; r < 4; r++) acc[g][n][r] *= alr[r];
      }
      const float m = mrun[g];
      float sum = 0.f;
#pragma unroll
      for (int t8 = 0; t8 < 8; t8++) {
#pragma unroll
        for (int r = 0; r < 4; r++) {
          float pv = __expf(st[t8][r] - m);
          st[t8][r] = pv;
          sum += pv;
        }
      }
      sum += __shfl_xor(sum, 16, 64);
      sum += __shfl_xor(sum, 32, 64);
      lsum[g] += sum;

      // P -> wave-local LDS: row q16, keys t8*16+4*g4+0..3 as one b64
      // (bf16 pairs), swizzled by (q16&7)<<4. No barrier: wave-local DS order.
#pragma unroll
      for (int t8 = 0; t8 < 8; t8++) {
        unsigned plo = ((unsigned)f2bf(st[t8][1]) << 16) | f2bf(st[t8][0]);
        unsigned phi = ((unsigned)f2bf(st[t8][3]) << 16) | f2bf(st[t8][2]);
        uint2 w2 = {plo, phi};
        *(uint2*)(pb + q16 * 256 + ((t8 * 32 + g4 * 8) ^ ((q16 & 7) << 4))) = w2;
      }

      // PV A-fragments: R10's verified read (row q16, same XOR involution)
      bf16x8 pa[4];
#pragma unroll
      for (int kc = 0; kc < 4; kc++)
        pa[kc] = *(const bf16x8*)(pb + ((q16 * 256 + kc * 64 + lk16) ^ ((q16 & 7) << 4)));

      // PV: O += P[16x128] @ V[128x64] (V from LDS)
#pragma unroll
      for (int n = 0; n < 4; n++) {
        int vr = n * 16 + q16;
        int sw = (vr & 7) << 4;
        const char* vp = vb + vr * 256;
#pragma unroll
        for (int kc = 0; kc < 4; kc++) {
          bf16x8 vbv = *(const bf16x8*)(vp + ((kc * 64 + lk16) ^ sw));
          acc[g][n] = mfma16(pa[kc], vbv, acc[g][n]);
        }
      }
    }
  }

  // epilogue: O / l -> bf16 fused
#pragma unroll
  for (int g = 0; g < 2; g++) {
    float lr4[4];
#pragma unroll
    for (int r = 0; r < 4; r++) lr4[r] = __shfl(lsum[g], 4 * g4 + r, 64);
    const size_t orow0 = (size_t)b * 1024 + qt * 128 + wave * 32 + g * 16 + g4 * 4;
#pragma unroll
    for (int n = 0; n < 4; n++) {
      int col = outColBase + h * 64 + n * 16 + q16;
#pragma unroll
      for (int r = 0; r < 4; r++) {
        float o = acc[g][n][r] / lr4[r];
        Out[(orow0 + r) * 2048 + col] = f2bf(o);
      }
    }
  }
}

// ---------------------------------------------------------------------------
// In-place LayerNorm over rows of 1024 fp32 (1 block = 1 row, 256 thr)
// ---------------------------------------------------------------------------
__global__ __launch_bounds__(256) void ln_inplace(float* __restrict__ io,
                                                  const float* __restrict__ gamma,
                                                  const float* __restrict__ beta) {
  __shared__ float red[8];
  int row = blockIdx.x, tid = threadIdx.x;
  float* p = io + (size_t)row * 1024;
  float4 x = ((const float4*)p)[tid];
  float s = x.x + x.y + x.z + x.w;
  float s2 = x.x * x.x + x.y * x.y + x.z * x.z + x.w * x.w;
#pragma unroll
  for (int off = 32; off; off >>= 1) {
    s += __shfl_down(s, off, 64);
    s2 += __shfl_down(s2, off, 64);
  }
  int wv = tid >> 6;
  if ((tid & 63) == 0) { red[wv] = s; red[4 + wv] = s2; }
  __syncthreads();
  if (tid == 0) {
    red[0] = red[0] + red[1] + red[2] + red[3];
    red[4] = red[4] + red[5] + red[6] + red[7];
  }
  __syncthreads();
  float mu = red[0] * (1.f / 1024.f);
  float var = red[4] * (1.f / 1024.f) - mu * mu;
  float inv = rsqrtf(var + 1e-5f);
  float4 g = ((const float4*)gamma)[tid];
  float4 bb = ((const float4*)beta)[tid];
  x.x = (x.x - mu) * inv * g.x + bb.x;
  x.y = (x.y - mu) * inv * g.y + bb.y;
  x.z = (x.z - mu) * inv * g.z + bb.z;
  x.w = (x.w - mu) * inv * g.w + bb.w;
  ((float4*)p)[tid] = x;
}

// ---------------------------------------------------------------------------
extern "C" void kernel_launch(void* const* d_in, const int* in_sizes, int n_in,
                              void* d_out, int out_size, void* d_ws, size_t ws_size,
                              hipStream_t stream) {
  (void)in_sizes; (void)n_in; (void)out_size; (void)ws_size;
  const float* image = (const float*)d_in[0];
  const float* wavef = (const float*)d_in[1];
  const float* Wq_i  = (const float*)d_in[2];
  const float* bq_i  = (const float*)d_in[3];
  const float* Wkv_w = (const float*)d_in[4];
  const float* bkv_w = (const float*)d_in[5];
  const float* Wq_w  = (const float*)d_in[6];
  const float* bq_w  = (const float*)d_in[7];
  const float* Wkv_i = (const float*)d_in[8];
  const float* bkv_i = (const float*)d_in[9];
  const float* Wp    = (const float*)d_in[10];
  const float* bp    = (const float*)d_in[11];
  const float* gamma = (const float*)d_in[12];
  const float* beta  = (const float*)d_in[13];
  float* out = (float*)d_out;

  char* ws = (char*)d_ws;
  unsigned short* Xi = (unsigned short*)ws;                       // 8 MiB
  unsigned short* Xw = (unsigned short*)ws + 4096ull * 1024;      // 8 MiB
  unsigned short* fused = (unsigned short*)ws;                    // 16 MiB alias
  size_t off = 16ull << 20;
  auto take = [&](size_t bytes) { void* p = ws + off; off += bytes; return p; };
  unsigned short* Wt_qi  = (unsigned short*)take(2ull << 20);
  unsigned short* Wt_kvw = (unsigned short*)take(4ull << 20);
  unsigned short* Wt_qw  = (unsigned short*)take(2ull << 20);
  unsigned short* Wt_kvi = (unsigned short*)take(4ull << 20);
  unsigned short* Wt_p   = (unsigned short*)take(4ull << 20);
  unsigned short* q_s    = (unsigned short*)take(8ull << 20);
  unsigned short* q_f    = (unsigned short*)take(8ull << 20);
  unsigned short* kvK_w  = (unsigned short*)take(8ull << 20);
  unsigned short* VtG_w  = (unsigned short*)take(8ull << 20);
  unsigned short* kvK_s  = (unsigned short*)take(8ull << 20);
  unsigned short* VtG_s  = (unsigned short*)take(8ull << 20);

  // 1) convert both activations to bf16
  cvt2_kernel<<<8192, 256, 0, stream>>>(image, Xi, wavef, Xw);
  // 2) all 5 weight transposes
  TransArgs ta;
  ta.W[0] = Wq_i;  ta.Wt[0] = Wt_qi;
  ta.W[1] = Wkv_w; ta.Wt[1] = Wt_kvw;
  ta.W[2] = Wq_w;  ta.Wt[2] = Wt_qw;
  ta.W[3] = Wkv_i; ta.Wt[3] = Wt_kvi;
  ta.W[4] = Wp;    ta.Wt[4] = Wt_p;
  transpose_all<<<8192, 256, 0, stream>>>(ta);
  // 3) projections
  gemm_q2<<<dim3(8, 16, 2), 512, 0, stream>>>(Xi, Wt_qi, bq_i, q_s,
                                              Xw, Wt_qw, bq_w, q_f);
  gemm_kv2<<<dim3(16, 32, 2), 512, 0, stream>>>(Xw, Wt_kvw, bkv_w, kvK_w, VtG_w,
                                                Xi, Wt_kvi, bkv_i, kvK_s, VtG_s);
  // 4) fused dual-direction cross attention (one launch)
  attn_fused<<<dim3(16, 64), 256, 0, stream>>>(q_s, kvK_w, VtG_w,
                                               q_f, kvK_s, VtG_s, fused);
  // 5) output projection + 6) LayerNorm
  gemm_out<<<dim3(8, 32), 512, 0, stream>>>(fused, Wt_p, bp, out);
  ln_inplace<<<4096, 256, 0, stream>>>(out, gamma, beta);
}

// Round 18
// 199.324 us; speedup vs baseline: 1.3513x; 1.0501x over previous
//
#include <hip/hip_runtime.h>
#include <hip/hip_bf16.h>

#define DEVINL __device__ __forceinline__

typedef float f32x4 __attribute__((ext_vector_type(4)));
typedef __bf16 bf16x8 __attribute__((ext_vector_type(8)));

DEVINL void gld_lds16(const void* g, void* l) {
  __builtin_amdgcn_global_load_lds(
      (const __attribute__((address_space(1))) unsigned int*)g,
      (__attribute__((address_space(3))) unsigned int*)l, 16, 0, 0);
}

DEVINL unsigned short f2bf(float f) {
  __bf16 h = (__bf16)f;
  return __builtin_bit_cast(unsigned short, h);
}

DEVINL f32x4 mfma16(bf16x8 a, bf16x8 b, f32x4 c) {
  return __builtin_amdgcn_mfma_f32_16x16x32_bf16(a, b, c, 0, 0, 0);
}

// XCD-aware bijective block remap (nwg divisible by 8).
DEVINL void swz3(int& bn, int& bm, int& z) {
  int gx = gridDim.x, gy = gridDim.y;
  int nwg = gx * gy * gridDim.z;
  int flat = blockIdx.x + gx * (blockIdx.y + gy * blockIdx.z);
  int wg = (flat & 7) * (nwg >> 3) + (flat >> 3);
  bn = wg % gx;
  int t = wg / gx;
  bm = t % gy;
  z = t / gy;
}

// ---------------------------------------------------------------------------
// fp32 -> bf16 convert, both activations in one launch (grid 8192 x 256)
// ---------------------------------------------------------------------------
__global__ __launch_bounds__(256) void cvt2_kernel(const float* __restrict__ inA,
                                                   unsigned short* __restrict__ outA,
                                                   const float* __restrict__ inB,
                                                   unsigned short* __restrict__ outB) {
  int bx = blockIdx.x;
  const float* in = bx < 4096 ? inA : inB;
  unsigned short* outp = bx < 4096 ? outA : outB;
  int i = (bx & 4095) * 256 + threadIdx.x;
  float4 v = ((const float4*)in)[i];
  ushort4 o;
  o.x = f2bf(v.x); o.y = f2bf(v.y); o.z = f2bf(v.z); o.w = f2bf(v.w);
  ((ushort4*)outp)[i] = o;
}

// ---------------------------------------------------------------------------
// All 5 weight transposes (W[K][N] fp32 -> Wt[N][K] bf16) in one launch.
// ---------------------------------------------------------------------------
struct TransArgs {
  const float* W[5];
  unsigned short* Wt[5];
};

DEVINL void trans_tile(const float* W, unsigned short* Wt, int K, int N,
                       int xt, int yt) {
  __shared__ float t[32][33];
  int n0 = xt * 32, k0 = yt * 32;
  int tx = threadIdx.x & 31, ty = threadIdx.x >> 5;  // ty 0..7
#pragma unroll
  for (int i = 0; i < 4; i++)
    t[ty + i * 8][tx] = W[(size_t)(k0 + ty + i * 8) * N + n0 + tx];
  __syncthreads();
#pragma unroll
  for (int i = 0; i < 4; i++) {
    int n = ty + i * 8;
    Wt[(size_t)(n0 + n) * K + k0 + tx] = f2bf(t[tx][n]);
  }
}

__global__ __launch_bounds__(256) void transpose_all(TransArgs a) {
  int t = blockIdx.x;
  if (t < 1024)       trans_tile(a.W[0], a.Wt[0], 1024, 1024, t % 32, t / 32);
  else if (t < 3072)  { int l = t - 1024; trans_tile(a.W[1], a.Wt[1], 1024, 2048, l % 64, l / 64); }
  else if (t < 4096)  { int l = t - 3072; trans_tile(a.W[2], a.Wt[2], 1024, 1024, l % 32, l / 32); }
  else if (t < 6144)  { int l = t - 4096; trans_tile(a.W[3], a.Wt[3], 1024, 2048, l % 64, l / 64); }
  else                { int l = t - 6144; trans_tile(a.W[4], a.Wt[4], 2048, 1024, l % 32, l / 32); }
}

// ---------------------------------------------------------------------------
// 8-wave GEMM main loop (BM x BN tile, BK=64, 512 threads, waves 2M x 4N).
// T2 XOR swizzle; double-buffered, one barrier per K-step (m97 order).
// ---------------------------------------------------------------------------
template <int BM, int BN, int MREP, int NREP>
DEVINL void g256_main(const unsigned short* A, const unsigned short* Bt, int K,
                      int bm, int bn, unsigned short* Al, unsigned short* Bl,
                      f32x4 (&acc)[MREP][NREP]) {
  const int tid = threadIdx.x;
  const int wave = tid >> 6, lane = tid & 63;
  const int lr = lane & 15;
  const int lk16 = (lane >> 4) * 16;
  const int wm = wave >> 2, wn = wave & 3;
  const int swz = (lr & 7) << 4;
  const int nk = K >> 6;
  const size_t Kb = (size_t)K * 2;

#pragma unroll
  for (int m = 0; m < MREP; m++)
#pragma unroll
    for (int n = 0; n < NREP; n++) acc[m][n] = f32x4{0.f, 0.f, 0.f, 0.f};

  auto stage = [&](int buf, int kt) {
#pragma unroll
    for (int i = 0; i < BM / 64; i++) {
      int chunk = i * 512 + tid;
      int row = chunk >> 3, cb = (chunk & 7) * 16;
      const char* src = (const char*)A + (size_t)(bm * BM + row) * Kb +
                        kt * 128 + (cb ^ ((row & 7) << 4));
      char* dst = (char*)(Al + (size_t)buf * BM * 64) + (i * 512 + wave * 64) * 16;
      gld_lds16(src, dst);
    }
#pragma unroll
    for (int i = 0; i < BN / 64; i++) {
      int chunk = i * 512 + tid;
      int row = chunk >> 3, cb = (chunk & 7) * 16;
      const char* src = (const char*)Bt + (size_t)(bn * BN + row) * Kb +
                        kt * 128 + (cb ^ ((row & 7) << 4));
      char* dst = (char*)(Bl + (size_t)buf * BN * 64) + (i * 512 + wave * 64) * 16;
      gld_lds16(src, dst);
    }
  };

  stage(0, 0);
  for (int kt = 0; kt < nk; ++kt) {
    __syncthreads();
    if (kt + 1 < nk) stage((kt + 1) & 1, kt + 1);
    const char* ab = (const char*)(Al + (size_t)(kt & 1) * BM * 64);
    const char* bb = (const char*)(Bl + (size_t)(kt & 1) * BN * 64);
#pragma unroll
    for (int kk = 0; kk < 2; kk++) {
      bf16x8 af[MREP], bf[NREP];
#pragma unroll
      for (int m = 0; m < MREP; m++) {
        int row = wm * (BM / 2) + m * 16 + lr;
        af[m] = *(const bf16x8*)(ab + row * 128 + ((kk * 64 + lk16) ^ swz));
      }
#pragma unroll
      for (int n = 0; n < NREP; n++) {
        int row = wn * (BN / 4) + n * 16 + lr;
        bf[n] = *(const bf16x8*)(bb + row * 128 + ((kk * 64 + lk16) ^ swz));
      }
#pragma unroll
      for (int m = 0; m < MREP; m++)
#pragma unroll
        for (int n = 0; n < NREP; n++)
          acc[m][n] = mfma16(af[m], bf[n], acc[m][n]);
    }
  }
}

// ---------------------------------------------------------------------------
// Dual Q-projection: 256x128 tile, grid (8,16,2) = 256 blocks.
// Epilogue folds the attention softmax scale 1/8 into Q (scores = q'.k).
// ---------------------------------------------------------------------------
__global__ __launch_bounds__(512, 2) void gemm_q2(const unsigned short* __restrict__ A0,
                                                  const unsigned short* __restrict__ B0,
                                                  const float* __restrict__ bias0,
                                                  unsigned short* __restrict__ C0,
                                                  const unsigned short* __restrict__ A1,
                                                  const unsigned short* __restrict__ B1,
                                                  const float* __restrict__ bias1,
                                                  unsigned short* __restrict__ C1) {
  __shared__ unsigned short Al[2 * 256 * 64];  // 64KB
  __shared__ unsigned short Bl[2 * 128 * 64];  // 32KB
  int bn, bm, z;
  swz3(bn, bm, z);
  const unsigned short* A = z ? A1 : A0;
  const unsigned short* Bt = z ? B1 : B0;
  const float* bias = z ? bias1 : bias0;
  unsigned short* C = z ? C1 : C0;
  const int lane = threadIdx.x & 63, wave = threadIdx.x >> 6;
  const int lr = lane & 15, g4 = lane >> 4;
  const int wm = wave >> 2, wn = wave & 3;
  f32x4 acc[8][2];
  g256_main<256, 128, 8, 2>(A, Bt, 1024, bm, bn, Al, Bl, acc);
#pragma unroll
  for (int n = 0; n < 2; n++) {
    int col = bn * 128 + wn * 32 + n * 16 + lr;
    float bv = bias[col];
#pragma unroll
    for (int m = 0; m < 8; m++) {
      int row0 = bm * 256 + wm * 128 + m * 16 + g4 * 4;
#pragma unroll
      for (int r = 0; r < 4; r++)
        C[(size_t)(row0 + r) * 1024 + col] = f2bf((acc[m][n][r] + bv) * 0.125f);
    }
  }
}

// ---------------------------------------------------------------------------
// Dual KV projection: 128x128 tile, 8 waves, grid (16,32,2) = 1024 blocks,
// LDS 64KB -> 2 blocks/CU. K half -> Kbuf; V half -> V^T [bh][64 d][1024 s].
// ---------------------------------------------------------------------------
__global__ __launch_bounds__(512, 4) void gemm_kv2(const unsigned short* __restrict__ A0,
                                                   const unsigned short* __restrict__ B0,
                                                   const float* __restrict__ bias0,
                                                   unsigned short* __restrict__ K0,
                                                   unsigned short* __restrict__ V0,
                                                   const unsigned short* __restrict__ A1,
                                                   const unsigned short* __restrict__ B1,
                                                   const float* __restrict__ bias1,
                                                   unsigned short* __restrict__ K1,
                                                   unsigned short* __restrict__ V1) {
  __shared__ unsigned short Al[2 * 128 * 64];  // 32KB
  __shared__ unsigned short Bl[2 * 128 * 64];  // 32KB
  int bn, bm, z;
  swz3(bn, bm, z);
  const unsigned short* A = z ? A1 : A0;
  const unsigned short* Bt = z ? B1 : B0;
  const float* bias = z ? bias1 : bias0;
  unsigned short* Kbuf = z ? K1 : K0;
  unsigned short* VtG = z ? V1 : V0;
  const int lane = threadIdx.x & 63, wave = threadIdx.x >> 6;
  const int lr = lane & 15, g4 = lane >> 4;
  const int wm = wave >> 2, wn = wave & 3;
  f32x4 acc[4][2];
  g256_main<128, 128, 4, 2>(A, Bt, 1024, bm, bn, Al, Bl, acc);
#pragma unroll
  for (int n = 0; n < 2; n++) {
    int col = bn * 128 + wn * 32 + n * 16 + lr;
    float bv = bias[col];
#pragma unroll
    for (int m = 0; m < 4; m++) {
      int row0 = bm * 128 + wm * 64 + m * 16 + g4 * 4;
      if (col < 1024) {
#pragma unroll
        for (int r = 0; r < 4; r++)
          Kbuf[(size_t)(row0 + r) * 1024 + col] = f2bf(acc[m][n][r] + bv);
      } else {
        int h = (col - 1024) >> 6, d = (col - 1024) & 63;
        int b = row0 >> 10, s = row0 & 1023;
        ushort4 pk;
        pk.x = f2bf(acc[m][n][0] + bv);
        pk.y = f2bf(acc[m][n][1] + bv);
        pk.z = f2bf(acc[m][n][2] + bv);
        pk.w = f2bf(acc[m][n][3] + bv);
        *(ushort4*)&VtG[((size_t)(b * 16 + h) * 64 + d) * 1024 + s] = pk;
      }
    }
  }
}

// ---------------------------------------------------------------------------
// Output projection: fused[4096][2048] @ Wt_p^T + bp -> fp32 out [4096][1024].
// 128x128 tile -> grid (8,32).
// ---------------------------------------------------------------------------
__global__ __launch_bounds__(512, 4) void gemm_out(const unsigned short* __restrict__ A,
                                                   const unsigned short* __restrict__ Bt,
                                                   const float* __restrict__ bias,
                                                   float* __restrict__ C) {
  __shared__ unsigned short Al[2 * 128 * 64];  // 32KB
  __shared__ unsigned short Bl[2 * 128 * 64];  // 32KB
  int bn, bm, z;
  swz3(bn, bm, z);
  const int lane = threadIdx.x & 63, wave = threadIdx.x >> 6;
  const int lr = lane & 15, g4 = lane >> 4;
  const int wm = wave >> 2, wn = wave & 3;
  f32x4 acc[4][2];
  g256_main<128, 128, 4, 2>(A, Bt, 2048, bm, bn, Al, Bl, acc);
#pragma unroll
  for (int n = 0; n < 2; n++) {
    int col = bn * 128 + wn * 32 + n * 16 + lr;
    float bv = bias[col];
#pragma unroll
    for (int m = 0; m < 4; m++) {
      int row0 = bm * 128 + wm * 64 + m * 16 + g4 * 4;
#pragma unroll
      for (int r = 0; r < 4; r++)
        C[(size_t)(row0 + r) * 1024 + col] = acc[m][n][r] + bv;
    }
  }
  (void)z;
}

// ---------------------------------------------------------------------------
// Fused dual-direction flash attention, QBLK=128, KVBLK=64 (LDS 40KB ->
// 4 blocks/CU, 4 waves/SIMD). In-register swapped-QK softmax + defer-max +
// wave-local LDS P transport (R17 structure; R12's verified KVBLK=64
// staging addresses). Scale pre-folded into Q. Grid (16,64).
// ---------------------------------------------------------------------------
__global__ __launch_bounds__(256, 4) void attn_fused(const unsigned short* __restrict__ Qs,
                                                     const unsigned short* __restrict__ Ks,
                                                     const unsigned short* __restrict__ Vs,
                                                     const unsigned short* __restrict__ Qf,
                                                     const unsigned short* __restrict__ Kf,
                                                     const unsigned short* __restrict__ Vf,
                                                     unsigned short* __restrict__ Out) {
  __shared__ unsigned short Kl[2][64 * 64];   // 16KB dbuf K tile [key][d]
  __shared__ unsigned short Vt[2][64 * 64];   // 16KB dbuf V^T tile [d][key]
  __shared__ unsigned short Pl[4][16 * 64];   // 8KB per-wave P (wave-local)

  const int tid = threadIdx.x;
  const int wave = tid >> 6, lane = tid & 63;
  const int qt = blockIdx.y & 7;
  const int u = blockIdx.x + (blockIdx.y >> 3) * 16;
  const int dir = u >> 6, bh = u & 63;
  const int b = bh >> 4, h = bh & 15;
  const unsigned short* Q = dir ? Qf : Qs;
  const unsigned short* Kg = dir ? Kf : Ks;
  const unsigned short* VtG = dir ? Vf : Vs;
  const int outColBase = dir ? 1024 : 0;
  const bool doClamp = (dir == 0);   // wave-uniform branch

  const int q16 = lane & 15;       // this lane's q-row (softmax) & output col
  const int g4 = lane >> 4;        // key-quarter group
  const int lk16 = g4 * 16;

  // Q fragments (B-operand): lane holds Q[q16][d-chunk g4*8..] (pre-scaled)
  bf16x8 qa[2][2];
#pragma unroll
  for (int g = 0; g < 2; g++) {
    const size_t qrow = (size_t)b * 1024 + qt * 128 + wave * 32 + g * 16 + q16;
    const char* qp = (const char*)(Q + qrow * 1024 + h * 64);
    qa[g][0] = *(const bf16x8*)(qp + lk16);
    qa[g][1] = *(const bf16x8*)(qp + 64 + lk16);
  }

  f32x4 acc[2][4] = {};
  float mrun[2] = {-1e30f, -1e30f}, lsum[2] = {0.f, 0.f};

  const char* kbase = (const char*)Kg + (size_t)b * 1024 * 2048 + h * 128;
  const char* vbase = (const char*)VtG + (size_t)bh * 64 * 2048;

  // stage 64-key tile kt (512 x 16B chunks, 2/thread), src pre-swizzled (R12)
  auto stage = [&](int buf, int kt) {
#pragma unroll
    for (int p2 = 0; p2 < 2; p2++) {
      int chunk = tid + p2 * 256;                  // 0..511
      int r = chunk >> 3, cb = (chunk & 7) * 16;   // key row 0..63, 16B col
      const char* src = kbase + (size_t)(kt * 64 + r) * 2048 + (cb ^ ((r & 7) << 4));
      char* dst = (char*)&Kl[buf][0] + (p2 * 256 + wave * 64) * 16;  // wave-uniform
      gld_lds16(src, dst);
    }
#pragma unroll
    for (int p2 = 0; p2 < 2; p2++) {
      int chunk = tid + p2 * 256;
      int d = chunk >> 3, ko = (chunk & 7) * 16;   // d row 0..63, 16B col
      const char* src = vbase + (size_t)d * 2048 + kt * 128 + (ko ^ ((d & 7) << 4));
      char* dst = (char*)&Vt[buf][0] + (p2 * 256 + wave * 64) * 16;  // wave-uniform
      gld_lds16(src, dst);
    }
  };

  char* pb = (char*)&Pl[wave][0];

  stage(0, 0);
  for (int kt = 0; kt < 16; ++kt) {
    __syncthreads();                 // stage(kt) complete; prev reads done
    if (kt < 15) stage((kt + 1) & 1, kt + 1);  // flies during compute(kt)
    const char* kb = (const char*)&Kl[kt & 1][0];
    const char* vb = (const char*)&Vt[kt & 1][0];

#pragma unroll
    for (int g = 0; g < 2; g++) {
      // swapped QK^T: st[t4][r] = S[key = t4*16 + 4*g4 + r][q16] (pre-scaled)
      f32x4 st[4];
#pragma unroll
      for (int t4 = 0; t4 < 4; t4++) {
        int krow = t4 * 16 + q16;
        int sw = (krow & 7) << 4;
        const char* kr = kb + krow * 128;
        bf16x8 kb0 = *(const bf16x8*)(kr + ((0 + lk16) ^ sw));
        bf16x8 kb1 = *(const bf16x8*)(kr + ((64 + lk16) ^ sw));
        f32x4 s = {};
        s = mfma16(kb0, qa[g][0], s);   // K as A, Q as B -> D[key][q]
        s = mfma16(kb1, qa[g][1], s);
        if (doClamp) {
#pragma unroll
          for (int r = 0; r < 4; r++)
            s[r] = fminf(fmaxf(s[r], -100.f), 100.f);
        }
        st[t4] = s;
      }

      // row-max for q=q16: local tree + 2 shfl
      float mx = fmaxf(fmaxf(fmaxf(st[0][0], st[0][1]), fmaxf(st[0][2], st[0][3])),
                       fmaxf(fmaxf(st[1][0], st[1][1]), fmaxf(st[1][2], st[1][3])));
      float mx2 = fmaxf(fmaxf(fmaxf(st[2][0], st[2][1]), fmaxf(st[2][2], st[2][3])),
                        fmaxf(fmaxf(st[3][0], st[3][1]), fmaxf(st[3][2], st[3][3])));
      mx = fmaxf(mx, mx2);
      mx = fmaxf(mx, __shfl_xor(mx, 16, 64));
      mx = fmaxf(mx, __shfl_xor(mx, 32, 64));

      // defer-max (T13, THR=8)
      if (!__all(mx <= mrun[g] + 8.f)) {
        float mnew = fmaxf(mrun[g], mx);
        float al = __expf(mrun[g] - mnew);
        mrun[g] = mnew;
        lsum[g] *= al;
        float alr[4];
#pragma unroll
        for (int r = 0; r < 4; r++) alr[r] = __shfl(al, 4 * g4 + r, 64);
#pragma unroll
        for (int n = 0; n < 4; n++)
#pragma unroll
          for (int r = 0; r < 4; r++) acc[g][n][r] *= alr[r];
      }
      const float m = mrun[g];
      float sum = 0.f;
#pragma unroll
      for (int t4 = 0; t4 < 4; t4++) {
#pragma unroll
        for (int r = 0; r < 4; r++) {
          float pv = __expf(st[t4][r] - m);
          st[t4][r] = pv;
          sum += pv;
        }
      }
      sum += __shfl_xor(sum, 16, 64);
      sum += __shfl_xor(sum, 32, 64);
      lsum[g] += sum;

      // P -> wave-local LDS: row q16 (128B), keys t4*16+4*g4+0..3 as one b64
#pragma unroll
      for (int t4 = 0; t4 < 4; t4++) {
        unsigned plo = ((unsigned)f2bf(st[t4][1]) << 16) | f2bf(st[t4][0]);
        unsigned phi = ((unsigned)f2bf(st[t4][3]) << 16) | f2bf(st[t4][2]);
        uint2 w2 = {plo, phi};
        *(uint2*)(pb + q16 * 128 + ((t4 * 32 + g4 * 8) ^ ((q16 & 7) << 4))) = w2;
      }

      // PV A-fragments (same XOR involution; wave-local DS order, no barrier)
      bf16x8 pa[2];
#pragma unroll
      for (int kc = 0; kc < 2; kc++)
        pa[kc] = *(const bf16x8*)(pb + ((q16 * 128 + kc * 64 + lk16) ^ ((q16 & 7) << 4)));

      // PV: O += P[16x64] @ V[64x64] (V from LDS)
#pragma unroll
      for (int n = 0; n < 4; n++) {
        int vr = n * 16 + q16;
        int sw = (vr & 7) << 4;
        const char* vp = vb + vr * 128;
#pragma unroll
        for (int kc = 0; kc < 2; kc++) {
          bf16x8 vbv = *(const bf16x8*)(vp + ((kc * 64 + lk16) ^ sw));
          acc[g][n] = mfma16(pa[kc], vbv, acc[g][n]);
        }
      }
    }
  }

  // epilogue: O / l -> bf16 fused
#pragma unroll
  for (int g = 0; g < 2; g++) {
    float lr4[4];
#pragma unroll
    for (int r = 0; r < 4; r++) lr4[r] = __shfl(lsum[g], 4 * g4 + r, 64);
    const size_t orow0 = (size_t)b * 1024 + qt * 128 + wave * 32 + g * 16 + g4 * 4;
#pragma unroll
    for (int n = 0; n < 4; n++) {
      int col = outColBase + h * 64 + n * 16 + q16;
#pragma unroll
      for (int r = 0; r < 4; r++) {
        float o = acc[g][n][r] / lr4[r];
        Out[(orow0 + r) * 2048 + col] = f2bf(o);
      }
    }
  }
}

// ---------------------------------------------------------------------------
// In-place LayerNorm over rows of 1024 fp32 (1 block = 1 row, 256 thr)
// ---------------------------------------------------------------------------
__global__ __launch_bounds__(256) void ln_inplace(float* __restrict__ io,
                                                  const float* __restrict__ gamma,
                                                  const float* __restrict__ beta) {
  __shared__ float red[8];
  int row = blockIdx.x, tid = threadIdx.x;
  float* p = io + (size_t)row * 1024;
  float4 x = ((const float4*)p)[tid];
  float s = x.x + x.y + x.z + x.w;
  float s2 = x.x * x.x + x.y * x.y + x.z * x.z + x.w * x.w;
#pragma unroll
  for (int off = 32; off; off >>= 1) {
    s += __shfl_down(s, off, 64);
    s2 += __shfl_down(s2, off, 64);
  }
  int wv = tid >> 6;
  if ((tid & 63) == 0) { red[wv] = s; red[4 + wv] = s2; }
  __syncthreads();
  if (tid == 0) {
    red[0] = red[0] + red[1] + red[2] + red[3];
    red[4] = red[4] + red[5] + red[6] + red[7];
  }
  __syncthreads();
  float mu = red[0] * (1.f / 1024.f);
  float var = red[4] * (1.f / 1024.f) - mu * mu;
  float inv = rsqrtf(var + 1e-5f);
  float4 g = ((const float4*)gamma)[tid];
  float4 bb = ((const float4*)beta)[tid];
  x.x = (x.x - mu) * inv * g.x + bb.x;
  x.y = (x.y - mu) * inv * g.y + bb.y;
  x.z = (x.z - mu) * inv * g.z + bb.z;
  x.w = (x.w - mu) * inv * g.w + bb.w;
  ((float4*)p)[tid] = x;
}

// ---------------------------------------------------------------------------
extern "C" void kernel_launch(void* const* d_in, const int* in_sizes, int n_in,
                              void* d_out, int out_size, void* d_ws, size_t ws_size,
                              hipStream_t stream) {
  (void)in_sizes; (void)n_in; (void)out_size; (void)ws_size;
  const float* image = (const float*)d_in[0];
  const float* wavef = (const float*)d_in[1];
  const float* Wq_i  = (const float*)d_in[2];
  const float* bq_i  = (const float*)d_in[3];
  const float* Wkv_w = (const float*)d_in[4];
  const float* bkv_w = (const float*)d_in[5];
  const float* Wq_w  = (const float*)d_in[6];
  const float* bq_w  = (const float*)d_in[7];
  const float* Wkv_i = (const float*)d_in[8];
  const float* bkv_i = (const float*)d_in[9];
  const float* Wp    = (const float*)d_in[10];
  const float* bp    = (const float*)d_in[11];
  const float* gamma = (const float*)d_in[12];
  const float* beta  = (const float*)d_in[13];
  float* out = (float*)d_out;

  char* ws = (char*)d_ws;
  unsigned short* Xi = (unsigned short*)ws;                       // 8 MiB
  unsigned short* Xw = (unsigned short*)ws + 4096ull * 1024;      // 8 MiB
  unsigned short* fused = (unsigned short*)ws;                    // 16 MiB alias
  size_t off = 16ull << 20;
  auto take = [&](size_t bytes) { void* p = ws + off; off += bytes; return p; };
  unsigned short* Wt_qi  = (unsigned short*)take(2ull << 20);
  unsigned short* Wt_kvw = (unsigned short*)take(4ull << 20);
  unsigned short* Wt_qw  = (unsigned short*)take(2ull << 20);
  unsigned short* Wt_kvi = (unsigned short*)take(4ull << 20);
  unsigned short* Wt_p   = (unsigned short*)take(4ull << 20);
  unsigned short* q_s    = (unsigned short*)take(8ull << 20);
  unsigned short* q_f    = (unsigned short*)take(8ull << 20);
  unsigned short* kvK_w  = (unsigned short*)take(8ull << 20);
  unsigned short* VtG_w  = (unsigned short*)take(8ull << 20);
  unsigned short* kvK_s  = (unsigned short*)take(8ull << 20);
  unsigned short* VtG_s  = (unsigned short*)take(8ull << 20);

  // 1) convert both activations to bf16
  cvt2_kernel<<<8192, 256, 0, stream>>>(image, Xi, wavef, Xw);
  // 2) all 5 weight transposes
  TransArgs ta;
  ta.W[0] = Wq_i;  ta.Wt[0] = Wt_qi;
  ta.W[1] = Wkv_w; ta.Wt[1] = Wt_kvw;
  ta.W[2] = Wq_w;  ta.Wt[2] = Wt_qw;
  ta.W[3] = Wkv_i; ta.Wt[3] = Wt_kvi;
  ta.W[4] = Wp;    ta.Wt[4] = Wt_p;
  transpose_all<<<8192, 256, 0, stream>>>(ta);
  // 3) projections
  gemm_q2<<<dim3(8, 16, 2), 512, 0, stream>>>(Xi, Wt_qi, bq_i, q_s,
                                              Xw, Wt_qw, bq_w, q_f);
  gemm_kv2<<<dim3(16, 32, 2), 512, 0, stream>>>(Xw, Wt_kvw, bkv_w, kvK_w, VtG_w,
                                                Xi, Wt_kvi, bkv_i, kvK_s, VtG_s);
  // 4) fused dual-direction cross attention (one launch, 4 blocks/CU)
  attn_fused<<<dim3(16, 64), 256, 0, stream>>>(q_s, kvK_w, VtG_w,
                                               q_f, kvK_s, VtG_s, fused);
  // 5) output projection + 6) LayerNorm
  gemm_out<<<dim3(8, 32), 512, 0, stream>>>(fused, Wt_p, bp, out);
  ln_inplace<<<4096, 256, 0, stream>>>(out, gamma, beta);
}

// Round 19
// 174.412 us; speedup vs baseline: 1.5444x; 1.1428x over previous
//
#include <hip/hip_runtime.h>
#include <hip/hip_bf16.h>

#define DEVINL __device__ __forceinline__

typedef float f32x4 __attribute__((ext_vector_type(4)));
typedef __bf16 bf16x8 __attribute__((ext_vector_type(8)));

DEVINL void gld_lds16(const void* g, void* l) {
  __builtin_amdgcn_global_load_lds(
      (const __attribute__((address_space(1))) unsigned int*)g,
      (__attribute__((address_space(3))) unsigned int*)l, 16, 0, 0);
}

DEVINL unsigned short f2bf(float f) {
  __bf16 h = (__bf16)f;
  return __builtin_bit_cast(unsigned short, h);
}

DEVINL f32x4 mfma16(bf16x8 a, bf16x8 b, f32x4 c) {
  return __builtin_amdgcn_mfma_f32_16x16x32_bf16(a, b, c, 0, 0, 0);
}

// XCD-aware bijective block remap (nwg divisible by 8).
DEVINL void swz3(int& bn, int& bm, int& z) {
  int gx = gridDim.x, gy = gridDim.y;
  int nwg = gx * gy * gridDim.z;
  int flat = blockIdx.x + gx * (blockIdx.y + gy * blockIdx.z);
  int wg = (flat & 7) * (nwg >> 3) + (flat >> 3);
  bn = wg % gx;
  int t = wg / gx;
  bm = t % gy;
  z = t / gy;
}

// ---------------------------------------------------------------------------
// Prep: both fp32->bf16 activation converts AND all 5 weight transposes in
// one launch. Grid 16384 x 256: t<8192 cvt, else transpose tile (t-8192).
// ---------------------------------------------------------------------------
struct PrepArgs {
  const float* inA; unsigned short* outA;   // image -> Xi
  const float* inB; unsigned short* outB;   // wavef -> Xw
  const float* W[5];
  unsigned short* Wt[5];
};

DEVINL void trans_tile(const float* W, unsigned short* Wt, int K, int N,
                       int xt, int yt) {
  __shared__ float t[32][33];
  int n0 = xt * 32, k0 = yt * 32;
  int tx = threadIdx.x & 31, ty = threadIdx.x >> 5;  // ty 0..7
#pragma unroll
  for (int i = 0; i < 4; i++)
    t[ty + i * 8][tx] = W[(size_t)(k0 + ty + i * 8) * N + n0 + tx];
  __syncthreads();
#pragma unroll
  for (int i = 0; i < 4; i++) {
    int n = ty + i * 8;
    Wt[(size_t)(n0 + n) * K + k0 + tx] = f2bf(t[tx][n]);
  }
}

__global__ __launch_bounds__(256) void prep_all(PrepArgs a) {
  int t = blockIdx.x;
  if (t < 8192) {
    const float* in = t < 4096 ? a.inA : a.inB;
    unsigned short* outp = t < 4096 ? a.outA : a.outB;
    int i = (t & 4095) * 256 + threadIdx.x;
    float4 v = ((const float4*)in)[i];
    ushort4 o;
    o.x = f2bf(v.x); o.y = f2bf(v.y); o.z = f2bf(v.z); o.w = f2bf(v.w);
    ((ushort4*)outp)[i] = o;
    return;
  }
  t -= 8192;
  if (t < 1024)       trans_tile(a.W[0], a.Wt[0], 1024, 1024, t % 32, t / 32);
  else if (t < 3072)  { int l = t - 1024; trans_tile(a.W[1], a.Wt[1], 1024, 2048, l % 64, l / 64); }
  else if (t < 4096)  { int l = t - 3072; trans_tile(a.W[2], a.Wt[2], 1024, 1024, l % 32, l / 32); }
  else if (t < 6144)  { int l = t - 4096; trans_tile(a.W[3], a.Wt[3], 1024, 2048, l % 64, l / 64); }
  else                { int l = t - 6144; trans_tile(a.W[4], a.Wt[4], 2048, 1024, l % 32, l / 32); }
}

// ---------------------------------------------------------------------------
// 8-wave GEMM main loop (BM x BN tile, BK=64, 512 threads, waves 2M x 4N).
// T2 XOR swizzle; double-buffered, one barrier per K-step (m97 order).
// ---------------------------------------------------------------------------
template <int BM, int BN, int MREP, int NREP>
DEVINL void g256_main(const unsigned short* A, const unsigned short* Bt, int K,
                      int bm, int bn, unsigned short* Al, unsigned short* Bl,
                      f32x4 (&acc)[MREP][NREP]) {
  const int tid = threadIdx.x;
  const int wave = tid >> 6, lane = tid & 63;
  const int lr = lane & 15;
  const int lk16 = (lane >> 4) * 16;
  const int wm = wave >> 2, wn = wave & 3;
  const int swz = (lr & 7) << 4;
  const int nk = K >> 6;
  const size_t Kb = (size_t)K * 2;

#pragma unroll
  for (int m = 0; m < MREP; m++)
#pragma unroll
    for (int n = 0; n < NREP; n++) acc[m][n] = f32x4{0.f, 0.f, 0.f, 0.f};

  auto stage = [&](int buf, int kt) {
#pragma unroll
    for (int i = 0; i < BM / 64; i++) {
      int chunk = i * 512 + tid;
      int row = chunk >> 3, cb = (chunk & 7) * 16;
      const char* src = (const char*)A + (size_t)(bm * BM + row) * Kb +
                        kt * 128 + (cb ^ ((row & 7) << 4));
      char* dst = (char*)(Al + (size_t)buf * BM * 64) + (i * 512 + wave * 64) * 16;
      gld_lds16(src, dst);
    }
#pragma unroll
    for (int i = 0; i < BN / 64; i++) {
      int chunk = i * 512 + tid;
      int row = chunk >> 3, cb = (chunk & 7) * 16;
      const char* src = (const char*)Bt + (size_t)(bn * BN + row) * Kb +
                        kt * 128 + (cb ^ ((row & 7) << 4));
      char* dst = (char*)(Bl + (size_t)buf * BN * 64) + (i * 512 + wave * 64) * 16;
      gld_lds16(src, dst);
    }
  };

  stage(0, 0);
  for (int kt = 0; kt < nk; ++kt) {
    __syncthreads();
    if (kt + 1 < nk) stage((kt + 1) & 1, kt + 1);
    const char* ab = (const char*)(Al + (size_t)(kt & 1) * BM * 64);
    const char* bb = (const char*)(Bl + (size_t)(kt & 1) * BN * 64);
#pragma unroll
    for (int kk = 0; kk < 2; kk++) {
      bf16x8 af[MREP], bf[NREP];
#pragma unroll
      for (int m = 0; m < MREP; m++) {
        int row = wm * (BM / 2) + m * 16 + lr;
        af[m] = *(const bf16x8*)(ab + row * 128 + ((kk * 64 + lk16) ^ swz));
      }
#pragma unroll
      for (int n = 0; n < NREP; n++) {
        int row = wn * (BN / 4) + n * 16 + lr;
        bf[n] = *(const bf16x8*)(bb + row * 128 + ((kk * 64 + lk16) ^ swz));
      }
#pragma unroll
      for (int m = 0; m < MREP; m++)
#pragma unroll
        for (int n = 0; n < NREP; n++)
          acc[m][n] = mfma16(af[m], bf[n], acc[m][n]);
    }
  }
}

// ---------------------------------------------------------------------------
// Unified projection GEMM: grid (16,32,3) = 1536 blocks, 128x128 tiles,
// 64KB LDS -> 2 blocks/CU. z=0: Xw@Wkv_w -> K_w/V^T_w; z=1: Xi@Wkv_i ->
// K_s/V^T_s; z=2: bn<8 -> Xi@Wq_i -> q_s, bn>=8 -> Xw@Wq_w -> q_f (x1/8).
// ---------------------------------------------------------------------------
__global__ __launch_bounds__(512, 4) void gemm_proj(
    const unsigned short* __restrict__ Xi, const unsigned short* __restrict__ Xw,
    const unsigned short* __restrict__ Wt_qi, const float* __restrict__ bq_i,
    unsigned short* __restrict__ q_s,
    const unsigned short* __restrict__ Wt_qw, const float* __restrict__ bq_w,
    unsigned short* __restrict__ q_f,
    const unsigned short* __restrict__ Wt_kvw, const float* __restrict__ bkv_w,
    unsigned short* __restrict__ K_w, unsigned short* __restrict__ V_w,
    const unsigned short* __restrict__ Wt_kvi, const float* __restrict__ bkv_i,
    unsigned short* __restrict__ K_s, unsigned short* __restrict__ V_s) {
  __shared__ unsigned short Al[2 * 128 * 64];  // 32KB
  __shared__ unsigned short Bl[2 * 128 * 64];  // 32KB
  int bn, bm, z;
  swz3(bn, bm, z);
  const int lane = threadIdx.x & 63, wave = threadIdx.x >> 6;
  const int lr = lane & 15, g4 = lane >> 4;
  const int wm = wave >> 2, wn = wave & 3;
  f32x4 acc[4][2];

  if (z == 2) {
    // Q projections (N=1024): bn<8 -> set S (image), else set F (waveform)
    const bool isS = bn < 8;
    const unsigned short* A = isS ? Xi : Xw;
    const unsigned short* Bt = isS ? Wt_qi : Wt_qw;
    const float* bias = isS ? bq_i : bq_w;
    unsigned short* C = isS ? q_s : q_f;
    const int bq = bn & 7;
    g256_main<128, 128, 4, 2>(A, Bt, 1024, bm, bq, Al, Bl, acc);
#pragma unroll
    for (int n = 0; n < 2; n++) {
      int col = bq * 128 + wn * 32 + n * 16 + lr;
      float bv = bias[col];
#pragma unroll
      for (int m = 0; m < 4; m++) {
        int row0 = bm * 128 + wm * 64 + m * 16 + g4 * 4;
#pragma unroll
        for (int r = 0; r < 4; r++)
          C[(size_t)(row0 + r) * 1024 + col] = f2bf((acc[m][n][r] + bv) * 0.125f);
      }
    }
  } else {
    // KV projections (N=2048): K half -> Kbuf; V half -> V^T [bh][d][s]
    const unsigned short* A = z ? Xi : Xw;
    const unsigned short* Bt = z ? Wt_kvi : Wt_kvw;
    const float* bias = z ? bkv_i : bkv_w;
    unsigned short* Kbuf = z ? K_s : K_w;
    unsigned short* VtG = z ? V_s : V_w;
    g256_main<128, 128, 4, 2>(A, Bt, 1024, bm, bn, Al, Bl, acc);
#pragma unroll
    for (int n = 0; n < 2; n++) {
      int col = bn * 128 + wn * 32 + n * 16 + lr;
      float bv = bias[col];
#pragma unroll
      for (int m = 0; m < 4; m++) {
        int row0 = bm * 128 + wm * 64 + m * 16 + g4 * 4;
        if (col < 1024) {
#pragma unroll
          for (int r = 0; r < 4; r++)
            Kbuf[(size_t)(row0 + r) * 1024 + col] = f2bf(acc[m][n][r] + bv);
        } else {
          int h = (col - 1024) >> 6, d = (col - 1024) & 63;
          int b = row0 >> 10, s = row0 & 1023;
          ushort4 pk;
          pk.x = f2bf(acc[m][n][0] + bv);
          pk.y = f2bf(acc[m][n][1] + bv);
          pk.z = f2bf(acc[m][n][2] + bv);
          pk.w = f2bf(acc[m][n][3] + bv);
          *(ushort4*)&VtG[((size_t)(b * 16 + h) * 64 + d) * 1024 + s] = pk;
        }
      }
    }
  }
}

// ---------------------------------------------------------------------------
// Output projection: fused[4096][2048] @ Wt_p^T + bp -> fp32 out [4096][1024].
// 128x64 tile, grid (16,32) = 512 blocks -> 2 blocks/CU (drain overlap).
// ---------------------------------------------------------------------------
__global__ __launch_bounds__(512, 4) void gemm_out(const unsigned short* __restrict__ A,
                                                   const unsigned short* __restrict__ Bt,
                                                   const float* __restrict__ bias,
                                                   float* __restrict__ C) {
  __shared__ unsigned short Al[2 * 128 * 64];  // 32KB
  __shared__ unsigned short Bl[2 * 64 * 64];   // 16KB
  int bn, bm, z;
  swz3(bn, bm, z);
  const int lane = threadIdx.x & 63, wave = threadIdx.x >> 6;
  const int lr = lane & 15, g4 = lane >> 4;
  const int wm = wave >> 2, wn = wave & 3;
  f32x4 acc[4][1];
  g256_main<128, 64, 4, 1>(A, Bt, 2048, bm, bn, Al, Bl, acc);
  int col = bn * 64 + wn * 16 + lr;
  float bv = bias[col];
#pragma unroll
  for (int m = 0; m < 4; m++) {
    int row0 = bm * 128 + wm * 64 + m * 16 + g4 * 4;
#pragma unroll
    for (int r = 0; r < 4; r++)
      C[(size_t)(row0 + r) * 1024 + col] = acc[m][0][r] + bv;
  }
  (void)z;
}

// ---------------------------------------------------------------------------
// Fused dual-direction flash attention, QBLK=128, KVBLK=64 (LDS 40KB ->
// 4 blocks/CU). In-register swapped-QK softmax + defer-max + wave-local LDS
// P transport. Scale pre-folded into Q. T5 setprio around MFMA clusters.
// ---------------------------------------------------------------------------
__global__ __launch_bounds__(256, 4) void attn_fused(const unsigned short* __restrict__ Qs,
                                                     const unsigned short* __restrict__ Ks,
                                                     const unsigned short* __restrict__ Vs,
                                                     const unsigned short* __restrict__ Qf,
                                                     const unsigned short* __restrict__ Kf,
                                                     const unsigned short* __restrict__ Vf,
                                                     unsigned short* __restrict__ Out) {
  __shared__ unsigned short Kl[2][64 * 64];   // 16KB dbuf K tile [key][d]
  __shared__ unsigned short Vt[2][64 * 64];   // 16KB dbuf V^T tile [d][key]
  __shared__ unsigned short Pl[4][16 * 64];   // 8KB per-wave P (wave-local)

  const int tid = threadIdx.x;
  const int wave = tid >> 6, lane = tid & 63;
  const int qt = blockIdx.y & 7;
  const int u = blockIdx.x + (blockIdx.y >> 3) * 16;
  const int dir = u >> 6, bh = u & 63;
  const int b = bh >> 4, h = bh & 15;
  const unsigned short* Q = dir ? Qf : Qs;
  const unsigned short* Kg = dir ? Kf : Ks;
  const unsigned short* VtG = dir ? Vf : Vs;
  const int outColBase = dir ? 1024 : 0;
  const bool doClamp = (dir == 0);   // wave-uniform branch

  const int q16 = lane & 15;
  const int g4 = lane >> 4;
  const int lk16 = g4 * 16;

  bf16x8 qa[2][2];
#pragma unroll
  for (int g = 0; g < 2; g++) {
    const size_t qrow = (size_t)b * 1024 + qt * 128 + wave * 32 + g * 16 + q16;
    const char* qp = (const char*)(Q + qrow * 1024 + h * 64);
    qa[g][0] = *(const bf16x8*)(qp + lk16);
    qa[g][1] = *(const bf16x8*)(qp + 64 + lk16);
  }

  f32x4 acc[2][4] = {};
  float mrun[2] = {-1e30f, -1e30f}, lsum[2] = {0.f, 0.f};

  const char* kbase = (const char*)Kg + (size_t)b * 1024 * 2048 + h * 128;
  const char* vbase = (const char*)VtG + (size_t)bh * 64 * 2048;

  auto stage = [&](int buf, int kt) {
#pragma unroll
    for (int p2 = 0; p2 < 2; p2++) {
      int chunk = tid + p2 * 256;                  // 0..511
      int r = chunk >> 3, cb = (chunk & 7) * 16;
      const char* src = kbase + (size_t)(kt * 64 + r) * 2048 + (cb ^ ((r & 7) << 4));
      char* dst = (char*)&Kl[buf][0] + (p2 * 256 + wave * 64) * 16;
      gld_lds16(src, dst);
    }
#pragma unroll
    for (int p2 = 0; p2 < 2; p2++) {
      int chunk = tid + p2 * 256;
      int d = chunk >> 3, ko = (chunk & 7) * 16;
      const char* src = vbase + (size_t)d * 2048 + kt * 128 + (ko ^ ((d & 7) << 4));
      char* dst = (char*)&Vt[buf][0] + (p2 * 256 + wave * 64) * 16;
      gld_lds16(src, dst);
    }
  };

  char* pb = (char*)&Pl[wave][0];

  stage(0, 0);
  for (int kt = 0; kt < 16; ++kt) {
    __syncthreads();
    if (kt < 15) stage((kt + 1) & 1, kt + 1);
    const char* kb = (const char*)&Kl[kt & 1][0];
    const char* vb = (const char*)&Vt[kt & 1][0];

#pragma unroll
    for (int g = 0; g < 2; g++) {
      // swapped QK^T (pre-scaled Q)
      f32x4 st[4];
      __builtin_amdgcn_s_setprio(1);
#pragma unroll
      for (int t4 = 0; t4 < 4; t4++) {
        int krow = t4 * 16 + q16;
        int sw = (krow & 7) << 4;
        const char* kr = kb + krow * 128;
        bf16x8 kb0 = *(const bf16x8*)(kr + ((0 + lk16) ^ sw));
        bf16x8 kb1 = *(const bf16x8*)(kr + ((64 + lk16) ^ sw));
        f32x4 s = {};
        s = mfma16(kb0, qa[g][0], s);
        s = mfma16(kb1, qa[g][1], s);
        st[t4] = s;
      }
      __builtin_amdgcn_s_setprio(0);
      if (doClamp) {
#pragma unroll
        for (int t4 = 0; t4 < 4; t4++)
#pragma unroll
          for (int r = 0; r < 4; r++)
            st[t4][r] = fminf(fmaxf(st[t4][r], -100.f), 100.f);
      }

      // row-max: local tree + 2 shfl
      float mx = fmaxf(fmaxf(fmaxf(st[0][0], st[0][1]), fmaxf(st[0][2], st[0][3])),
                       fmaxf(fmaxf(st[1][0], st[1][1]), fmaxf(st[1][2], st[1][3])));
      float mx2 = fmaxf(fmaxf(fmaxf(st[2][0], st[2][1]), fmaxf(st[2][2], st[2][3])),
                        fmaxf(fmaxf(st[3][0], st[3][1]), fmaxf(st[3][2], st[3][3])));
      mx = fmaxf(mx, mx2);
      mx = fmaxf(mx, __shfl_xor(mx, 16, 64));
      mx = fmaxf(mx, __shfl_xor(mx, 32, 64));

      // defer-max (T13, THR=8)
      if (!__all(mx <= mrun[g] + 8.f)) {
        float mnew = fmaxf(mrun[g], mx);
        float al = __expf(mrun[g] - mnew);
        mrun[g] = mnew;
        lsum[g] *= al;
        float alr[4];
#pragma unroll
        for (int r = 0; r < 4; r++) alr[r] = __shfl(al, 4 * g4 + r, 64);
#pragma unroll
        for (int n = 0; n < 4; n++)
#pragma unroll
          for (int r = 0; r < 4; r++) acc[g][n][r] *= alr[r];
      }
      const float m = mrun[g];
      float sum = 0.f;
#pragma unroll
      for (int t4 = 0; t4 < 4; t4++) {
#pragma unroll
        for (int r = 0; r < 4; r++) {
          float pv = __expf(st[t4][r] - m);
          st[t4][r] = pv;
          sum += pv;
        }
      }
      sum += __shfl_xor(sum, 16, 64);
      sum += __shfl_xor(sum, 32, 64);
      lsum[g] += sum;

      // P -> wave-local LDS (128B rows, XOR involution)
#pragma unroll
      for (int t4 = 0; t4 < 4; t4++) {
        unsigned plo = ((unsigned)f2bf(st[t4][1]) << 16) | f2bf(st[t4][0]);
        unsigned phi = ((unsigned)f2bf(st[t4][3]) << 16) | f2bf(st[t4][2]);
        uint2 w2 = {plo, phi};
        *(uint2*)(pb + q16 * 128 + ((t4 * 32 + g4 * 8) ^ ((q16 & 7) << 4))) = w2;
      }

      bf16x8 pa[2];
#pragma unroll
      for (int kc = 0; kc < 2; kc++)
        pa[kc] = *(const bf16x8*)(pb + ((q16 * 128 + kc * 64 + lk16) ^ ((q16 & 7) << 4)));

      // PV: O += P[16x64] @ V[64x64]
      __builtin_amdgcn_s_setprio(1);
#pragma unroll
      for (int n = 0; n < 4; n++) {
        int vr = n * 16 + q16;
        int sw = (vr & 7) << 4;
        const char* vp = vb + vr * 128;
#pragma unroll
        for (int kc = 0; kc < 2; kc++) {
          bf16x8 vbv = *(const bf16x8*)(vp + ((kc * 64 + lk16) ^ sw));
          acc[g][n] = mfma16(pa[kc], vbv, acc[g][n]);
        }
      }
      __builtin_amdgcn_s_setprio(0);
    }
  }

  // epilogue: O / l -> bf16 fused
#pragma unroll
  for (int g = 0; g < 2; g++) {
    float lr4[4];
#pragma unroll
    for (int r = 0; r < 4; r++) lr4[r] = __shfl(lsum[g], 4 * g4 + r, 64);
    const size_t orow0 = (size_t)b * 1024 + qt * 128 + wave * 32 + g * 16 + g4 * 4;
#pragma unroll
    for (int n = 0; n < 4; n++) {
      int col = outColBase + h * 64 + n * 16 + q16;
#pragma unroll
      for (int r = 0; r < 4; r++) {
        float o = acc[g][n][r] / lr4[r];
        Out[(orow0 + r) * 2048 + col] = f2bf(o);
      }
    }
  }
}

// ---------------------------------------------------------------------------
// In-place LayerNorm over rows of 1024 fp32 (1 block = 1 row, 256 thr)
// ---------------------------------------------------------------------------
__global__ __launch_bounds__(256) void ln_inplace(float* __restrict__ io,
                                                  const float* __restrict__ gamma,
                                                  const float* __restrict__ beta) {
  __shared__ float red[8];
  int row = blockIdx.x, tid = threadIdx.x;
  float* p = io + (size_t)row * 1024;
  float4 x = ((const float4*)p)[tid];
  float s = x.x + x.y + x.z + x.w;
  float s2 = x.x * x.x + x.y * x.y + x.z * x.z + x.w * x.w;
#pragma unroll
  for (int off = 32; off; off >>= 1) {
    s += __shfl_down(s, off, 64);
    s2 += __shfl_down(s2, off, 64);
  }
  int wv = tid >> 6;
  if ((tid & 63) == 0) { red[wv] = s; red[4 + wv] = s2; }
  __syncthreads();
  if (tid == 0) {
    red[0] = red[0] + red[1] + red[2] + red[3];
    red[4] = red[4] + red[5] + red[6] + red[7];
  }
  __syncthreads();
  float mu = red[0] * (1.f / 1024.f);
  float var = red[4] * (1.f / 1024.f) - mu * mu;
  float inv = rsqrtf(var + 1e-5f);
  float4 g = ((const float4*)gamma)[tid];
  float4 bb = ((const float4*)beta)[tid];
  x.x = (x.x - mu) * inv * g.x + bb.x;
  x.y = (x.y - mu) * inv * g.y + bb.y;
  x.z = (x.z - mu) * inv * g.z + bb.z;
  x.w = (x.w - mu) * inv * g.w + bb.w;
  ((float4*)p)[tid] = x;
}

// ---------------------------------------------------------------------------
extern "C" void kernel_launch(void* const* d_in, const int* in_sizes, int n_in,
                              void* d_out, int out_size, void* d_ws, size_t ws_size,
                              hipStream_t stream) {
  (void)in_sizes; (void)n_in; (void)out_size; (void)ws_size;
  const float* image = (const float*)d_in[0];
  const float* wavef = (const float*)d_in[1];
  const float* Wq_i  = (const float*)d_in[2];
  const float* bq_i  = (const float*)d_in[3];
  const float* Wkv_w = (const float*)d_in[4];
  const float* bkv_w = (const float*)d_in[5];
  const float* Wq_w  = (const float*)d_in[6];
  const float* bq_w  = (const float*)d_in[7];
  const float* Wkv_i = (const float*)d_in[8];
  const float* bkv_i = (const float*)d_in[9];
  const float* Wp    = (const float*)d_in[10];
  const float* bp    = (const float*)d_in[11];
  const float* gamma = (const float*)d_in[12];
  const float* beta  = (const float*)d_in[13];
  float* out = (float*)d_out;

  char* ws = (char*)d_ws;
  unsigned short* Xi = (unsigned short*)ws;                       // 8 MiB
  unsigned short* Xw = (unsigned short*)ws + 4096ull * 1024;      // 8 MiB
  unsigned short* fused = (unsigned short*)ws;                    // 16 MiB alias
  size_t off = 16ull << 20;
  auto take = [&](size_t bytes) { void* p = ws + off; off += bytes; return p; };
  unsigned short* Wt_qi  = (unsigned short*)take(2ull << 20);
  unsigned short* Wt_kvw = (unsigned short*)take(4ull << 20);
  unsigned short* Wt_qw  = (unsigned short*)take(2ull << 20);
  unsigned short* Wt_kvi = (unsigned short*)take(4ull << 20);
  unsigned short* Wt_p   = (unsigned short*)take(4ull << 20);
  unsigned short* q_s    = (unsigned short*)take(8ull << 20);
  unsigned short* q_f    = (unsigned short*)take(8ull << 20);
  unsigned short* kvK_w  = (unsigned short*)take(8ull << 20);
  unsigned short* VtG_w  = (unsigned short*)take(8ull << 20);
  unsigned short* kvK_s  = (unsigned short*)take(8ull << 20);
  unsigned short* VtG_s  = (unsigned short*)take(8ull << 20);

  // 1+2) prep: activation converts + weight transposes (one launch)
  PrepArgs pa;
  pa.inA = image; pa.outA = Xi;
  pa.inB = wavef; pa.outB = Xw;
  pa.W[0] = Wq_i;  pa.Wt[0] = Wt_qi;
  pa.W[1] = Wkv_w; pa.Wt[1] = Wt_kvw;
  pa.W[2] = Wq_w;  pa.Wt[2] = Wt_qw;
  pa.W[3] = Wkv_i; pa.Wt[3] = Wt_kvi;
  pa.W[4] = Wp;    pa.Wt[4] = Wt_p;
  prep_all<<<16384, 256, 0, stream>>>(pa);
  // 3) all projections (one launch, 1536 blocks, 2 blocks/CU)
  gemm_proj<<<dim3(16, 32, 3), 512, 0, stream>>>(
      Xi, Xw, Wt_qi, bq_i, q_s, Wt_qw, bq_w, q_f,
      Wt_kvw, bkv_w, kvK_w, VtG_w, Wt_kvi, bkv_i, kvK_s, VtG_s);
  // 4) fused dual-direction cross attention (4 blocks/CU, setprio)
  attn_fused<<<dim3(16, 64), 256, 0, stream>>>(q_s, kvK_w, VtG_w,
                                               q_f, kvK_s, VtG_s, fused);
  // 5) output projection (128x64 tiles, 512 blocks) + 6) LayerNorm
  gemm_out<<<dim3(16, 32), 512, 0, stream>>>(fused, Wt_p, bp, out);
  ln_inplace<<<4096, 256, 0, stream>>>(out, gamma, beta);
}